// Round 2
// baseline (978.617 us; speedup 1.0000x reference)
//
#include <hip/hip_runtime.h>
#include <math.h>

// ---------------------------------------------------------------------------
// StrategicGNN forward: MLP encoders -> 3x GATv2 -> MLP enhancer -> LayerNorm
// GEMMs via fp16x3-split MFMA (A*W^T ~= Ah*Wh + Ah*Wl + Al*Wh, ~fp32 accuracy)
// Edge phase (CSR build, logits/softmax/aggregate) in fp32.
// ---------------------------------------------------------------------------

static inline int ceildiv(int a, int b) { return (a + b - 1) / b; }

typedef _Float16 h8  __attribute__((ext_vector_type(8)));
typedef _Float16 h4v __attribute__((ext_vector_type(4)));
typedef float    f4x __attribute__((ext_vector_type(4)));

// ---- small utility ---------------------------------------------------------
__global__ void fill_u32(unsigned int* __restrict__ p, int n, unsigned int v) {
    int i = blockIdx.x * blockDim.x + threadIdx.x;
    if (i < n) p[i] = v;
}

// monotone float<->uint map so atomicMax(uint) implements float max.
// sentinel 0 acts as -inf (every node has a self-loop so always overwritten).
__device__ __forceinline__ unsigned int fmap(float f) {
    unsigned int u = __float_as_uint(f);
    return (u & 0x80000000u) ? ~u : (u | 0x80000000u);
}
__device__ __forceinline__ float funmap(unsigned int u) {
    return (u & 0x80000000u) ? __uint_as_float(u ^ 0x80000000u)
                             : __uint_as_float(~u);
}

// ---- fused hi/lo split of raw inputs + all weight matrices -----------------
struct SplitArgs {
    const float* src[14];
    _Float16* dh[14];
    _Float16* dl[14];
    int off[15];          // prefix sums, float4 units
};

__global__ void split_multi(SplitArgs a, int totalv) {
    int v = blockIdx.x * blockDim.x + threadIdx.x;
    if (v >= totalv) return;
    int s = 0;
#pragma unroll
    for (int i = 1; i < 14; i++) s += (v >= a.off[i]);
    int lv = v - a.off[s];
    float4 f = ((const float4*)a.src[s])[lv];
    float vals[4] = {f.x, f.y, f.z, f.w};
    h4v hh, hl;
#pragma unroll
    for (int j = 0; j < 4; j++) {
        _Float16 h = (_Float16)vals[j];
        hh[j] = h;
        hl[j] = (_Float16)(vals[j] - (float)h);
    }
    *(h4v*)(a.dh[s] + (size_t)lv * 4) = hh;
    *(h4v*)(a.dl[s] + (size_t)lv * 4) = hl;
}

// ---- MFMA GEMM: C[M,Ncols] = act(A[M,K] @ W[Ncols,K]^T + bias) -------------
// A,W given as fp16 hi/lo pairs. Tile 128x64, BK=64, 4 waves (64x32 each).
// LDS XOR-swizzled at 16B granularity to avoid 16-way bank conflicts.
// OUTMODE 0: fp32 out (Cf). OUTMODE 1: fp16 hi/lo pair out (Chi/Clo).
template <int OUTMODE, bool RELU>
__global__ __launch_bounds__(256) void gemm_mfma(
    const _Float16* __restrict__ Ahi, const _Float16* __restrict__ Alo,
    const _Float16* __restrict__ Whi, const _Float16* __restrict__ Wlo,
    const float* __restrict__ bias, float* __restrict__ Cf,
    _Float16* __restrict__ Chi, _Float16* __restrict__ Clo,
    int M, int K, int ldc)
{
    __shared__ _Float16 sA[2][128][64];   // [hi/lo][row][k]
    __shared__ _Float16 sW[2][64][64];
    const int t = threadIdx.x;
    const int lane = t & 63;
    const int w = t >> 6, wr = w >> 1, wc = w & 1;   // 2x2 waves of 64x32
    const int m0 = blockIdx.y * 128, n0 = blockIdx.x * 64;

    f4x acc[4][2] = {};

    for (int k0 = 0; k0 < K; k0 += 64) {
        // stage A tile (128x64 halves, hi+lo): 4 vec16 per thread per half
#pragma unroll
        for (int i = 0; i < 4; i++) {
            int v = t + 256 * i;                 // 0..1023
            int row = v >> 3, c8 = v & 7;        // 8 vec16 per row
            int gr = m0 + row; if (gr > M - 1) gr = M - 1;   // clamp tail
            size_t gidx = (size_t)gr * K + k0 + c8 * 8;
            h8 ah = *(const h8*)(Ahi + gidx);
            h8 al = *(const h8*)(Alo + gidx);
            int cs = ((c8 ^ (row & 7)) << 3);    // 16B-granular XOR swizzle
            *(h8*)&sA[0][row][cs] = ah;
            *(h8*)&sA[1][row][cs] = al;
        }
        // stage W tile (64x64 halves, hi+lo): 2 vec16 per thread per half
#pragma unroll
        for (int i = 0; i < 2; i++) {
            int v = t + 256 * i;                 // 0..511
            int row = v >> 3, c8 = v & 7;
            size_t gidx = (size_t)(n0 + row) * K + k0 + c8 * 8;
            h8 wh = *(const h8*)(Whi + gidx);
            h8 wl = *(const h8*)(Wlo + gidx);
            int cs = ((c8 ^ (row & 7)) << 3);
            *(h8*)&sW[0][row][cs] = wh;
            *(h8*)&sW[1][row][cs] = wl;
        }
        __syncthreads();
#pragma unroll
        for (int ks = 0; ks < 2; ks++) {        // two K=32 slices per BK=64
            const int kg = ks * 4 + (lane >> 4);   // vec16 index along k
            h8 afh[4], afl[4], wfh[2], wfl[2];
#pragma unroll
            for (int mi = 0; mi < 4; mi++) {
                int row = wr * 64 + mi * 16 + (lane & 15);
                int cs = ((kg ^ (row & 7)) << 3);
                afh[mi] = *(const h8*)&sA[0][row][cs];
                afl[mi] = *(const h8*)&sA[1][row][cs];
            }
#pragma unroll
            for (int ni = 0; ni < 2; ni++) {
                int row = wc * 32 + ni * 16 + (lane & 15);
                int cs = ((kg ^ (row & 7)) << 3);
                wfh[ni] = *(const h8*)&sW[0][row][cs];
                wfl[ni] = *(const h8*)&sW[1][row][cs];
            }
#pragma unroll
            for (int mi = 0; mi < 4; mi++)
#pragma unroll
                for (int ni = 0; ni < 2; ni++) {
                    acc[mi][ni] = __builtin_amdgcn_mfma_f32_16x16x32_f16(
                        afh[mi], wfh[ni], acc[mi][ni], 0, 0, 0);
                    acc[mi][ni] = __builtin_amdgcn_mfma_f32_16x16x32_f16(
                        afh[mi], wfl[ni], acc[mi][ni], 0, 0, 0);
                    acc[mi][ni] = __builtin_amdgcn_mfma_f32_16x16x32_f16(
                        afl[mi], wfh[ni], acc[mi][ni], 0, 0, 0);
                }
        }
        __syncthreads();
    }
    // epilogue: C/D layout col=lane&15, row=(lane>>4)*4+reg  [m89-verified]
#pragma unroll
    for (int mi = 0; mi < 4; mi++) {
#pragma unroll
        for (int ni = 0; ni < 2; ni++) {
            int col = n0 + wc * 32 + ni * 16 + (lane & 15);
            float bz = bias ? bias[col] : 0.f;
#pragma unroll
            for (int r = 0; r < 4; r++) {
                int grow = m0 + wr * 64 + mi * 16 + (lane >> 4) * 4 + r;
                if (grow < M) {
                    float vv = acc[mi][ni][r] + bz;
                    if (RELU) vv = fmaxf(vv, 0.f);
                    if (OUTMODE == 0) {
                        Cf[(size_t)grow * ldc + col] = vv;
                    } else {
                        _Float16 h = (_Float16)vv;
                        Chi[(size_t)grow * ldc + col] = h;
                        Clo[(size_t)grow * ldc + col] = (_Float16)(vv - (float)h);
                    }
                }
            }
        }
    }
}

// ---- CSR build (dst-sorted incidence; self-loop e in [E, E+N) ) ------------
__global__ void edge_count(const int* __restrict__ ei, int E, int ET,
                           int* __restrict__ cnt) {
    int e = blockIdx.x * blockDim.x + threadIdx.x;
    if (e >= ET) return;
    int dst = (e < E) ? ei[E + e] : e - E;
    atomicAdd(&cnt[dst], 1);
}

__global__ __launch_bounds__(1024) void scan_offsets(
    const int* __restrict__ cnt, int n, int* __restrict__ off,
    int* __restrict__ cur)
{
    __shared__ int s[1024];
    const int t = threadIdx.x;
    const int CH = (n + 1023) / 1024;
    int base = t * CH;
    int local[32];
    int sum = 0;
    for (int j = 0; j < CH; j++) {
        int idx = base + j;
        int v = (idx < n) ? cnt[idx] : 0;
        local[j] = sum;
        sum += v;
    }
    s[t] = sum;
    __syncthreads();
    for (int d = 1; d < 1024; d <<= 1) {
        int v = (t >= d) ? s[t - d] : 0;
        __syncthreads();
        s[t] += v;
        __syncthreads();
    }
    int excl = s[t] - sum;
    for (int j = 0; j < CH; j++) {
        int idx = base + j;
        if (idx < n) { off[idx] = excl + local[j]; cur[idx] = excl + local[j]; }
    }
    if (t == 1023) off[n] = s[1023];
}

__global__ void edge_scatter(const int* __restrict__ ei, int E, int ET,
                             int* __restrict__ cur, int* __restrict__ eid) {
    int e = blockIdx.x * blockDim.x + threadIdx.x;
    if (e >= ET) return;
    int dst = (e < E) ? ei[E + e] : e - E;
    int pos = atomicAdd(&cur[dst], 1);
    eid[pos] = e;
}

// ---- GATv2 edge logits: wave per edge --------------------------------------
template <int H, int C>
__global__ __launch_bounds__(256) void gat_logits(
    const float* __restrict__ xl, const float* __restrict__ xr,
    const float* __restrict__ att, const int* __restrict__ ei,
    int E, int ET, float* __restrict__ logits, unsigned int* __restrict__ mbuf)
{
    constexpr int HC = H * C;
    constexpr int R = HC / 64;
    const int wave = threadIdx.x >> 6;
    const int lane = threadIdx.x & 63;
    const int e = blockIdx.x * 4 + wave;
    if (e >= ET) return;
    int src, dst;
    if (e < E) { src = ei[e]; dst = ei[E + e]; } else { src = dst = e - E; }

    float part[R];
#pragma unroll
    for (int r = 0; r < R; r++) {
        int c = r * 64 + lane;
        float v = xl[(size_t)src * HC + c] + xr[(size_t)dst * HC + c];
        v = v > 0.f ? v : 0.2f * v;     // leaky_relu(., 0.2)
        part[r] = v * att[c];
    }
    if (H == 1) {
        float s = 0.f;
#pragma unroll
        for (int r = 0; r < R; r++) s += part[r];
#pragma unroll
        for (int off = 32; off >= 1; off >>= 1) s += __shfl_xor(s, off);
        if (lane == 0) {
            logits[(size_t)e * H] = s;
            atomicMax(&mbuf[(size_t)dst * H], fmap(s));
        }
    } else {
#pragma unroll
        for (int r = 0; r < R; r++)
#pragma unroll
            for (int off = 32; off >= 1; off >>= 1)
                part[r] += __shfl_xor(part[r], off);
        if (lane == 0) {
#pragma unroll
            for (int h = 0; h < H; h++) {
                logits[(size_t)e * H + h] = part[h];
                atomicMax(&mbuf[(size_t)dst * H + h], fmap(part[h]));
            }
        }
    }
}

// ---- p = exp(logit - max[dst]); denom += p ---------------------------------
template <int H>
__global__ void gat_p(const float* __restrict__ logits,
                      const unsigned int* __restrict__ mbuf,
                      const int* __restrict__ ei, int E, int ET,
                      float* __restrict__ pbuf, float* __restrict__ dbuf) {
    int idx = blockIdx.x * blockDim.x + threadIdx.x;
    if (idx >= ET * H) return;
    int e = idx / H, h = idx - e * H;
    int dst = (e < E) ? ei[E + e] : e - E;
    float m = funmap(mbuf[dst * H + h]);
    float p = expf(logits[idx] - m);
    pbuf[idx] = p;
    atomicAdd(&dbuf[dst * H + h], p);
}

// ---- aggregation over CSR: wave per dst node; fp16-pair epilogue -----------
template <int H, int C, bool RELU>
__global__ __launch_bounds__(256) void gat_agg_pair(
    const float* __restrict__ xl, const float* __restrict__ pbuf,
    const float* __restrict__ dbuf, const float* __restrict__ bias,
    const int* __restrict__ ei, const int* __restrict__ off,
    const int* __restrict__ eid, int E, int Nn,
    _Float16* __restrict__ oh, _Float16* __restrict__ ol)
{
    constexpr int HC = H * C;
    constexpr int R = HC / 64;
    const int wave = threadIdx.x >> 6;
    const int lane = threadIdx.x & 63;
    const int i = blockIdx.x * 4 + wave;
    if (i >= Nn) return;

    float dinv[R];
#pragma unroll
    for (int r = 0; r < R; r++) {
        int h = (C == 64) ? r : 0;
        dinv[r] = 1.f / dbuf[i * H + h];
    }
    float acc[R] = {};
    const int j0 = off[i], j1 = off[i + 1];
    for (int j = j0; j < j1; j++) {
        int e = eid[j];
        int s = (e < E) ? ei[e] : e - E;
#pragma unroll
        for (int r = 0; r < R; r++) {
            int h = (C == 64) ? r : 0;
            float alpha = pbuf[(size_t)e * H + h] * dinv[r];
            acc[r] += alpha * xl[(size_t)s * HC + r * 64 + lane];
        }
    }
#pragma unroll
    for (int r = 0; r < R; r++) {
        int c = r * 64 + lane;
        float v = acc[r] + bias[c];
        if (RELU) v = fmaxf(v, 0.f);
        _Float16 h = (_Float16)v;
        oh[(size_t)i * HC + c] = h;
        ol[(size_t)i * HC + c] = (_Float16)(v - (float)h);
    }
}

// ---- LayerNorm over 256 features: wave per row -----------------------------
__global__ __launch_bounds__(256) void layernorm256(
    const float* __restrict__ x, const float* __restrict__ g,
    const float* __restrict__ b, float* __restrict__ out, int Nn)
{
    const int wave = threadIdx.x >> 6;
    const int lane = threadIdx.x & 63;
    const int i = blockIdx.x * 4 + wave;
    if (i >= Nn) return;
    float v[4];
    float sum = 0.f;
#pragma unroll
    for (int r = 0; r < 4; r++) {
        v[r] = x[(size_t)i * 256 + r * 64 + lane];
        sum += v[r];
    }
#pragma unroll
    for (int off = 32; off >= 1; off >>= 1) sum += __shfl_xor(sum, off);
    float mu = sum * (1.f / 256.f);
    float s2 = 0.f;
#pragma unroll
    for (int r = 0; r < 4; r++) { float d = v[r] - mu; s2 += d * d; }
#pragma unroll
    for (int off = 32; off >= 1; off >>= 1) s2 += __shfl_xor(s2, off);
    float rstd = 1.f / sqrtf(s2 * (1.f / 256.f) + 1e-5f);
#pragma unroll
    for (int r = 0; r < 4; r++) {
        int c = r * 64 + lane;
        out[(size_t)i * 256 + c] = (v[r] - mu) * rstd * g[c] + b[c];
    }
}

// ---------------------------------------------------------------------------
extern "C" void kernel_launch(void* const* d_in, const int* in_sizes, int n_in,
                              void* d_out, int out_size, void* d_ws,
                              size_t ws_size, hipStream_t stream)
{
    const float* node_f = (const float*)d_in[0];
    const float* msg_f  = (const float*)d_in[1];
    const int*   ei     = (const int*)d_in[2];
    const float* wsrc[12] = {
        (const float*)d_in[3],  (const float*)d_in[5],   // me_w1, me_w2
        (const float*)d_in[7],  (const float*)d_in[9],   // ne_w1, ne_w2
        (const float*)d_in[11], (const float*)d_in[12],  // c1_wl, c1_wr
        (const float*)d_in[15], (const float*)d_in[16],  // c2_wl, c2_wr
        (const float*)d_in[19], (const float*)d_in[20],  // c3_wl, c3_wr
        (const float*)d_in[23], (const float*)d_in[25],  // en_w1, en_w2
    };
    const int wsz[12] = {256*256, 128*256, 128*128, 128*128,
                         256*256, 256*256, 128*256, 128*256,
                         256*128, 256*128, 512*256, 256*512};
    const float* me_b1 = (const float*)d_in[4];
    const float* me_b2 = (const float*)d_in[6];
    const float* ne_b1 = (const float*)d_in[8];
    const float* ne_b2 = (const float*)d_in[10];
    const float* c1_at = (const float*)d_in[13];
    const float* c1_b  = (const float*)d_in[14];
    const float* c2_at = (const float*)d_in[17];
    const float* c2_b  = (const float*)d_in[18];
    const float* c3_at = (const float*)d_in[21];
    const float* c3_b  = (const float*)d_in[22];
    const float* en_b1 = (const float*)d_in[24];
    const float* en_b2 = (const float*)d_in[26];
    const float* ln_g  = (const float*)d_in[27];
    const float* ln_b  = (const float*)d_in[28];

    const int N  = in_sizes[0] / 128;   // 20000
    const int E  = in_sizes[2] / 2;     // 320000
    const int ET = E + N;

    // ---- workspace regions (each SZ = N*256*4 bytes), aggressive aliasing --
    char* base = (char*)d_ws;
    const size_t SZ = (size_t)N * 256 * 4;
    char* RA = base;            // Pm pair            -> X1 pair (conv1 out)
    char* RB = base + SZ;       // Ph1 pair -> X3 pair (conv3 out) -> EN2 f32
    char* RC = base + 2 * SZ;   // Pn pair + Pnh pair -> X2 pair (conv2 out)
    char* RD = base + 3 * SZ;   // X0 pair (encoder concat out)
    char* RE = base + 4 * SZ;   // XL f32 -> HB hi
    char* RF = base + 5 * SZ;   // XR f32 -> HB lo
    char* RG = base + 6 * SZ;   // edge buffers + weight pairs

    _Float16* Pm_h = (_Float16*)RA;  _Float16* Pm_l = Pm_h + (size_t)N * 256;
    _Float16* X1_h = (_Float16*)RA;  _Float16* X1_l = X1_h + (size_t)N * 256;
    _Float16* Ph1_h = (_Float16*)RB; _Float16* Ph1_l = Ph1_h + (size_t)N * 256;
    _Float16* X3_h = (_Float16*)RB;  _Float16* X3_l = X3_h + (size_t)N * 256;
    float*    EN2  = (float*)RB;
    _Float16* Pn_h = (_Float16*)RC;  _Float16* Pn_l = Pn_h + (size_t)N * 128;
    _Float16* Pnh_h = Pn_l + (size_t)N * 128;
    _Float16* Pnh_l = Pnh_h + (size_t)N * 128;
    _Float16* X2_h = (_Float16*)RC;  _Float16* X2_l = X2_h + (size_t)N * 128;
    _Float16* X0_h = (_Float16*)RD;  _Float16* X0_l = X0_h + (size_t)N * 256;
    float* XL = (float*)RE;
    float* XR = (float*)RF;
    _Float16* HB_h = (_Float16*)RE;  // N*512 halves
    _Float16* HB_l = (_Float16*)RF;

    float* LOG = (float*)RG;
    float* PB  = LOG + (size_t)ET * 4;
    unsigned int* MB = (unsigned int*)(PB + (size_t)ET * 4);
    float* DB = (float*)(MB + (size_t)N * 4);
    int* CNT = (int*)(DB + (size_t)N * 4);
    int* OFF = CNT + N;
    int* CUR = OFF + N + 1;
    int* EID = CUR + N;
    _Float16* WP = (_Float16*)(EID + ET);

    // weight pair pointers
    _Float16 *wh[12], *wl[12];
    {
        _Float16* cur = WP;
        for (int i = 0; i < 12; i++) {
            wh[i] = cur; wl[i] = cur + wsz[i]; cur += 2 * (size_t)wsz[i];
        }
    }

    const dim3 B256(256);

    // ---- fused split: 12 weights + msg + node ----
    {
        SplitArgs sa;
        int cum = 0;
        for (int i = 0; i < 12; i++) {
            sa.src[i] = wsrc[i]; sa.dh[i] = wh[i]; sa.dl[i] = wl[i];
            sa.off[i] = cum; cum += wsz[i] / 4;
        }
        sa.src[12] = msg_f;  sa.dh[12] = Pm_h; sa.dl[12] = Pm_l;
        sa.off[12] = cum; cum += N * 256 / 4;
        sa.src[13] = node_f; sa.dh[13] = Pn_h; sa.dl[13] = Pn_l;
        sa.off[13] = cum; cum += N * 128 / 4;
        sa.off[14] = cum;
        split_multi<<<ceildiv(cum, 256), B256, 0, stream>>>(sa, cum);
    }

    // ---- CSR build (shared by all three convs) ----
    fill_u32<<<ceildiv(N, 256), B256, 0, stream>>>((unsigned int*)CNT, N, 0u);
    edge_count<<<ceildiv(ET, 256), B256, 0, stream>>>(ei, E, ET, CNT);
    scan_offsets<<<1, 1024, 0, stream>>>(CNT, N, OFF, CUR);
    edge_scatter<<<ceildiv(ET, 256), B256, 0, stream>>>(ei, E, ET, CUR, EID);

    const int MB_ = ceildiv(N, 128);   // GEMM grid rows (157)

    // ---- encoders -> X0 pair [N,256] = [node_emb | msg_emb] ----
    gemm_mfma<1, true ><<<dim3(4, MB_), B256, 0, stream>>>(
        Pm_h, Pm_l, wh[0], wl[0], me_b1, nullptr, Ph1_h, Ph1_l, N, 256, 256);
    gemm_mfma<1, false><<<dim3(2, MB_), B256, 0, stream>>>(
        Ph1_h, Ph1_l, wh[1], wl[1], me_b2, nullptr, X0_h + 128, X0_l + 128, N, 256, 256);
    gemm_mfma<1, true ><<<dim3(2, MB_), B256, 0, stream>>>(
        Pn_h, Pn_l, wh[2], wl[2], ne_b1, nullptr, Pnh_h, Pnh_l, N, 128, 128);
    gemm_mfma<1, false><<<dim3(2, MB_), B256, 0, stream>>>(
        Pnh_h, Pnh_l, wh[3], wl[3], ne_b2, nullptr, X0_h, X0_l, N, 128, 256);

    // ---- conv1: X0 (256) -> X1 pair (4 heads x 64, concat, relu) ----
    {
        fill_u32<<<ceildiv(N * 8, 256), B256, 0, stream>>>(MB, N * 8, 0u);
        gemm_mfma<0, false><<<dim3(4, MB_), B256, 0, stream>>>(
            X0_h, X0_l, wh[4], wl[4], nullptr, XL, nullptr, nullptr, N, 256, 256);
        gemm_mfma<0, false><<<dim3(4, MB_), B256, 0, stream>>>(
            X0_h, X0_l, wh[5], wl[5], nullptr, XR, nullptr, nullptr, N, 256, 256);
        gat_logits<4, 64><<<ceildiv(ET, 4), B256, 0, stream>>>(XL, XR, c1_at, ei, E, ET, LOG, MB);
        gat_p<4><<<ceildiv(ET * 4, 256), B256, 0, stream>>>(LOG, MB, ei, E, ET, PB, DB);
        gat_agg_pair<4, 64, true><<<ceildiv(N, 4), B256, 0, stream>>>(
            XL, PB, DB, c1_b, ei, OFF, EID, E, N, X1_h, X1_l);
    }

    // ---- conv2: X1 (256) -> X2 pair (2 heads x 64, concat, relu) ----
    {
        fill_u32<<<ceildiv(N * 8, 256), B256, 0, stream>>>(MB, N * 8, 0u);
        gemm_mfma<0, false><<<dim3(2, MB_), B256, 0, stream>>>(
            X1_h, X1_l, wh[6], wl[6], nullptr, XL, nullptr, nullptr, N, 256, 128);
        gemm_mfma<0, false><<<dim3(2, MB_), B256, 0, stream>>>(
            X1_h, X1_l, wh[7], wl[7], nullptr, XR, nullptr, nullptr, N, 256, 128);
        gat_logits<2, 64><<<ceildiv(ET, 4), B256, 0, stream>>>(XL, XR, c2_at, ei, E, ET, LOG, MB);
        gat_p<2><<<ceildiv(ET * 2, 256), B256, 0, stream>>>(LOG, MB, ei, E, ET, PB, DB);
        gat_agg_pair<2, 64, true><<<ceildiv(N, 4), B256, 0, stream>>>(
            XL, PB, DB, c2_b, ei, OFF, EID, E, N, X2_h, X2_l);
    }

    // ---- conv3: X2 (128) -> X3 pair (1 head x 256) ----
    {
        fill_u32<<<ceildiv(N * 8, 256), B256, 0, stream>>>(MB, N * 8, 0u);
        gemm_mfma<0, false><<<dim3(4, MB_), B256, 0, stream>>>(
            X2_h, X2_l, wh[8], wl[8], nullptr, XL, nullptr, nullptr, N, 128, 256);
        gemm_mfma<0, false><<<dim3(4, MB_), B256, 0, stream>>>(
            X2_h, X2_l, wh[9], wl[9], nullptr, XR, nullptr, nullptr, N, 128, 256);
        gat_logits<1, 256><<<ceildiv(ET, 4), B256, 0, stream>>>(XL, XR, c3_at, ei, E, ET, LOG, MB);
        gat_p<1><<<ceildiv(ET, 256), B256, 0, stream>>>(LOG, MB, ei, E, ET, PB, DB);
        gat_agg_pair<1, 256, false><<<ceildiv(N, 4), B256, 0, stream>>>(
            XL, PB, DB, c3_b, ei, OFF, EID, E, N, X3_h, X3_l);
    }

    // ---- enhancer: X3 -> HB pair (512, relu) -> EN2 f32 -> LN -> d_out ----
    gemm_mfma<1, true ><<<dim3(8, MB_), B256, 0, stream>>>(
        X3_h, X3_l, wh[10], wl[10], en_b1, nullptr, HB_h, HB_l, N, 256, 512);
    gemm_mfma<0, false><<<dim3(4, MB_), B256, 0, stream>>>(
        HB_h, HB_l, wh[11], wl[11], en_b2, EN2, nullptr, nullptr, N, 512, 256);
    layernorm256<<<ceildiv(N, 4), B256, 0, stream>>>(EN2, ln_g, ln_b, (float*)d_out, N);
}

// Round 3
// 740.698 us; speedup vs baseline: 1.3212x; 1.3212x over previous
//
#include <hip/hip_runtime.h>
#include <math.h>

// ---------------------------------------------------------------------------
// StrategicGNN forward: MLP encoders -> 3x GATv2 -> MLP enhancer -> LayerNorm
// GEMMs via fp16x3-split MFMA (A*W^T ~= Ah*Wh + Ah*Wl + Al*Wh, ~fp32 accuracy)
// Edge phase: single fused per-dst kernel over CSR (logits+softmax+aggregate),
// fp32 math, no atomics in the softmax path.
// ---------------------------------------------------------------------------

static inline int ceildiv(int a, int b) { return (a + b - 1) / b; }

typedef _Float16 h8  __attribute__((ext_vector_type(8)));
typedef _Float16 h4v __attribute__((ext_vector_type(4)));
typedef float    f4x __attribute__((ext_vector_type(4)));

// ---- small utility ---------------------------------------------------------
__global__ void fill_u32(unsigned int* __restrict__ p, int n, unsigned int v) {
    int i = blockIdx.x * blockDim.x + threadIdx.x;
    if (i < n) p[i] = v;
}

// ---- fused hi/lo split of raw inputs + all weight matrices -----------------
struct SplitArgs {
    const float* src[14];
    _Float16* dh[14];
    _Float16* dl[14];
    int off[15];          // prefix sums, float4 units
};

__global__ void split_multi(SplitArgs a, int totalv) {
    int v = blockIdx.x * blockDim.x + threadIdx.x;
    if (v >= totalv) return;
    int s = 0;
#pragma unroll
    for (int i = 1; i < 14; i++) s += (v >= a.off[i]);
    int lv = v - a.off[s];
    float4 f = ((const float4*)a.src[s])[lv];
    float vals[4] = {f.x, f.y, f.z, f.w};
    h4v hh, hl;
#pragma unroll
    for (int j = 0; j < 4; j++) {
        _Float16 h = (_Float16)vals[j];
        hh[j] = h;
        hl[j] = (_Float16)(vals[j] - (float)h);
    }
    *(h4v*)(a.dh[s] + (size_t)lv * 4) = hh;
    *(h4v*)(a.dl[s] + (size_t)lv * 4) = hl;
}

// ---- MFMA GEMM: C[M,Ncols] = act(A[M,K] @ W[Ncols,K]^T + bias) -------------
// A,W given as fp16 hi/lo pairs. Tile 128x64, BK=64, 4 waves (64x32 each).
// LDS XOR-swizzled at 16B granularity to avoid 16-way bank conflicts.
// OUTMODE 0: fp32 out (Cf). OUTMODE 1: fp16 hi/lo pair out (Chi/Clo).
template <int OUTMODE, bool RELU>
__global__ __launch_bounds__(256) void gemm_mfma(
    const _Float16* __restrict__ Ahi, const _Float16* __restrict__ Alo,
    const _Float16* __restrict__ Whi, const _Float16* __restrict__ Wlo,
    const float* __restrict__ bias, float* __restrict__ Cf,
    _Float16* __restrict__ Chi, _Float16* __restrict__ Clo,
    int M, int K, int ldc)
{
    __shared__ _Float16 sA[2][128][64];   // [hi/lo][row][k]
    __shared__ _Float16 sW[2][64][64];
    const int t = threadIdx.x;
    const int lane = t & 63;
    const int w = t >> 6, wr = w >> 1, wc = w & 1;   // 2x2 waves of 64x32
    const int m0 = blockIdx.y * 128, n0 = blockIdx.x * 64;

    f4x acc[4][2] = {};

    for (int k0 = 0; k0 < K; k0 += 64) {
        // stage A tile (128x64 halves, hi+lo): 4 vec16 per thread per half
#pragma unroll
        for (int i = 0; i < 4; i++) {
            int v = t + 256 * i;                 // 0..1023
            int row = v >> 3, c8 = v & 7;        // 8 vec16 per row
            int gr = m0 + row; if (gr > M - 1) gr = M - 1;   // clamp tail
            size_t gidx = (size_t)gr * K + k0 + c8 * 8;
            h8 ah = *(const h8*)(Ahi + gidx);
            h8 al = *(const h8*)(Alo + gidx);
            int cs = ((c8 ^ (row & 7)) << 3);    // 16B-granular XOR swizzle
            *(h8*)&sA[0][row][cs] = ah;
            *(h8*)&sA[1][row][cs] = al;
        }
        // stage W tile (64x64 halves, hi+lo): 2 vec16 per thread per half
#pragma unroll
        for (int i = 0; i < 2; i++) {
            int v = t + 256 * i;                 // 0..511
            int row = v >> 3, c8 = v & 7;
            size_t gidx = (size_t)(n0 + row) * K + k0 + c8 * 8;
            h8 wh = *(const h8*)(Whi + gidx);
            h8 wl = *(const h8*)(Wlo + gidx);
            int cs = ((c8 ^ (row & 7)) << 3);
            *(h8*)&sW[0][row][cs] = wh;
            *(h8*)&sW[1][row][cs] = wl;
        }
        __syncthreads();
#pragma unroll
        for (int ks = 0; ks < 2; ks++) {        // two K=32 slices per BK=64
            const int kg = ks * 4 + (lane >> 4);   // vec16 index along k
            h8 afh[4], afl[4], wfh[2], wfl[2];
#pragma unroll
            for (int mi = 0; mi < 4; mi++) {
                int row = wr * 64 + mi * 16 + (lane & 15);
                int cs = ((kg ^ (row & 7)) << 3);
                afh[mi] = *(const h8*)&sA[0][row][cs];
                afl[mi] = *(const h8*)&sA[1][row][cs];
            }
#pragma unroll
            for (int ni = 0; ni < 2; ni++) {
                int row = wc * 32 + ni * 16 + (lane & 15);
                int cs = ((kg ^ (row & 7)) << 3);
                wfh[ni] = *(const h8*)&sW[0][row][cs];
                wfl[ni] = *(const h8*)&sW[1][row][cs];
            }
#pragma unroll
            for (int mi = 0; mi < 4; mi++)
#pragma unroll
                for (int ni = 0; ni < 2; ni++) {
                    acc[mi][ni] = __builtin_amdgcn_mfma_f32_16x16x32_f16(
                        afh[mi], wfh[ni], acc[mi][ni], 0, 0, 0);
                    acc[mi][ni] = __builtin_amdgcn_mfma_f32_16x16x32_f16(
                        afh[mi], wfl[ni], acc[mi][ni], 0, 0, 0);
                    acc[mi][ni] = __builtin_amdgcn_mfma_f32_16x16x32_f16(
                        afl[mi], wfh[ni], acc[mi][ni], 0, 0, 0);
                }
        }
        __syncthreads();
    }
    // epilogue: C/D layout col=lane&15, row=(lane>>4)*4+reg  [m89-verified]
#pragma unroll
    for (int mi = 0; mi < 4; mi++) {
#pragma unroll
        for (int ni = 0; ni < 2; ni++) {
            int col = n0 + wc * 32 + ni * 16 + (lane & 15);
            float bz = bias ? bias[col] : 0.f;
#pragma unroll
            for (int r = 0; r < 4; r++) {
                int grow = m0 + wr * 64 + mi * 16 + (lane >> 4) * 4 + r;
                if (grow < M) {
                    float vv = acc[mi][ni][r] + bz;
                    if (RELU) vv = fmaxf(vv, 0.f);
                    if (OUTMODE == 0) {
                        Cf[(size_t)grow * ldc + col] = vv;
                    } else {
                        _Float16 h = (_Float16)vv;
                        Chi[(size_t)grow * ldc + col] = h;
                        Clo[(size_t)grow * ldc + col] = (_Float16)(vv - (float)h);
                    }
                }
            }
        }
    }
}

// ---- CSR build (dst-sorted incidence; self-loop e in [E, E+N) ) ------------
__global__ void edge_count(const int* __restrict__ ei, int E, int ET,
                           int* __restrict__ cnt) {
    int e = blockIdx.x * blockDim.x + threadIdx.x;
    if (e >= ET) return;
    int dst = (e < E) ? ei[E + e] : e - E;
    atomicAdd(&cnt[dst], 1);
}

__global__ __launch_bounds__(1024) void scan_offsets(
    const int* __restrict__ cnt, int n, int* __restrict__ off,
    int* __restrict__ cur)
{
    __shared__ int s[1024];
    const int t = threadIdx.x;
    const int CH = (n + 1023) / 1024;
    int base = t * CH;
    int local[32];
    int sum = 0;
    for (int j = 0; j < CH; j++) {
        int idx = base + j;
        int v = (idx < n) ? cnt[idx] : 0;
        local[j] = sum;
        sum += v;
    }
    s[t] = sum;
    __syncthreads();
    for (int d = 1; d < 1024; d <<= 1) {
        int v = (t >= d) ? s[t - d] : 0;
        __syncthreads();
        s[t] += v;
        __syncthreads();
    }
    int excl = s[t] - sum;
    for (int j = 0; j < CH; j++) {
        int idx = base + j;
        if (idx < n) { off[idx] = excl + local[j]; cur[idx] = excl + local[j]; }
    }
    if (t == 1023) off[n] = s[1023];
}

// scatter src ids into dst-sorted CSR order
__global__ void edge_scatter(const int* __restrict__ ei, int E, int ET,
                             int* __restrict__ cur, int* __restrict__ srcj) {
    int e = blockIdx.x * blockDim.x + threadIdx.x;
    if (e >= ET) return;
    int dst, src;
    if (e < E) { dst = ei[E + e]; src = ei[e]; } else { dst = src = e - E; }
    int pos = atomicAdd(&cur[dst], 1);
    srcj[pos] = src;
}

// ---- fused GATv2 layer: wave per dst node ----------------------------------
// Loop1: gather xl[src], logits -> logbuf[j*H+h] + running max (per head).
// Denom: in-wave reduction of exp(l - m). Loop2: re-gather xl (cache-hot),
// accumulate alpha*xl. Output written as fp16 hi/lo pair for the next GEMM.
// Feature->lane map: c = lane*R + r (R = H*C/64); head group = C/R lanes.
template <int H, int C, bool RELU>
__global__ __launch_bounds__(256) void gat_fused(
    const float* __restrict__ xl, const float* __restrict__ xr,
    const float* __restrict__ att, const float* __restrict__ bias,
    const int* __restrict__ srcj, const int* __restrict__ off,
    float* __restrict__ logbuf, int Nn,
    _Float16* __restrict__ oh, _Float16* __restrict__ ol)
{
    constexpr int HC = H * C;
    constexpr int R = HC / 64;                    // floats per lane (2 or 4)
    constexpr int G = C / R;                      // lanes per head group
    constexpr int LG = (G == 16) ? 4 : (G == 32) ? 5 : 6;
    const int wave = threadIdx.x >> 6;
    const int lane = threadIdx.x & 63;
    const int i = blockIdx.x * 4 + wave;
    if (i >= Nn) return;
    const int myh = lane >> LG;                   // my head
    const int j0 = off[i], j1 = off[i + 1];

    float xrv[R], attv[R];
#pragma unroll
    for (int r = 0; r < R; r++) {
        int c = lane * R + r;
        xrv[r] = xr[(size_t)i * HC + c];
        attv[r] = att[c];
    }

    // ---- pass 1: logits + per-head max ----
    float m = -INFINITY;
    for (int j = j0; j < j1; j++) {
        int s = srcj[j];
        const float* xp = xl + (size_t)s * HC + lane * R;
        float xv[R];
        if (R == 4) { float4 t4 = *(const float4*)xp;
                      xv[0]=t4.x; xv[1]=t4.y; xv[2]=t4.z; xv[3]=t4.w; }
        else        { float2 t2 = *(const float2*)xp; xv[0]=t2.x; xv[1]=t2.y; }
        float dot = 0.f;
#pragma unroll
        for (int r = 0; r < R; r++) {
            float v = xv[r] + xrv[r];
            v = v > 0.f ? v : 0.2f * v;           // leaky_relu(., 0.2)
            dot += v * attv[r];
        }
#pragma unroll
        for (int d = 1; d < G; d <<= 1) dot += __shfl_xor(dot, d);
        m = fmaxf(m, dot);
        if ((lane & (G - 1)) == 0) logbuf[(size_t)j * H + myh] = dot;
    }
    __threadfence_block();   // make lane0-of-group writes visible wave-wide

    // ---- denom: sum of exp(l - m) per head ----
    float ds = 0.f;
    for (int j = j0 + (lane & (G - 1)); j < j1; j += G)
        ds += expf(logbuf[(size_t)j * H + myh] - m);
#pragma unroll
    for (int d = 1; d < G; d <<= 1) ds += __shfl_xor(ds, d);
    const float rd = 1.f / ds;

    // ---- pass 2: aggregate alpha * xl[src] (cache-hot re-gather) ----
    float acc[R] = {};
    for (int j = j0; j < j1; j++) {
        int s = srcj[j];
        float alpha = expf(logbuf[(size_t)j * H + myh] - m) * rd;
        const float* xp = xl + (size_t)s * HC + lane * R;
        float xv[R];
        if (R == 4) { float4 t4 = *(const float4*)xp;
                      xv[0]=t4.x; xv[1]=t4.y; xv[2]=t4.z; xv[3]=t4.w; }
        else        { float2 t2 = *(const float2*)xp; xv[0]=t2.x; xv[1]=t2.y; }
#pragma unroll
        for (int r = 0; r < R; r++) acc[r] += alpha * xv[r];
    }

    // ---- epilogue: bias, relu, fp16 hi/lo pair ----
#pragma unroll
    for (int r = 0; r < R; r++) {
        int c = lane * R + r;
        float v = acc[r] + bias[c];
        if (RELU) v = fmaxf(v, 0.f);
        _Float16 h = (_Float16)v;
        oh[(size_t)i * HC + c] = h;
        ol[(size_t)i * HC + c] = (_Float16)(v - (float)h);
    }
}

// ---- LayerNorm over 256 features: wave per row -----------------------------
__global__ __launch_bounds__(256) void layernorm256(
    const float* __restrict__ x, const float* __restrict__ g,
    const float* __restrict__ b, float* __restrict__ out, int Nn)
{
    const int wave = threadIdx.x >> 6;
    const int lane = threadIdx.x & 63;
    const int i = blockIdx.x * 4 + wave;
    if (i >= Nn) return;
    float v[4];
    float sum = 0.f;
#pragma unroll
    for (int r = 0; r < 4; r++) {
        v[r] = x[(size_t)i * 256 + r * 64 + lane];
        sum += v[r];
    }
#pragma unroll
    for (int off = 32; off >= 1; off >>= 1) sum += __shfl_xor(sum, off);
    float mu = sum * (1.f / 256.f);
    float s2 = 0.f;
#pragma unroll
    for (int r = 0; r < 4; r++) { float d = v[r] - mu; s2 += d * d; }
#pragma unroll
    for (int off = 32; off >= 1; off >>= 1) s2 += __shfl_xor(s2, off);
    float rstd = 1.f / sqrtf(s2 * (1.f / 256.f) + 1e-5f);
#pragma unroll
    for (int r = 0; r < 4; r++) {
        int c = r * 64 + lane;
        out[(size_t)i * 256 + c] = (v[r] - mu) * rstd * g[c] + b[c];
    }
}

// ---------------------------------------------------------------------------
extern "C" void kernel_launch(void* const* d_in, const int* in_sizes, int n_in,
                              void* d_out, int out_size, void* d_ws,
                              size_t ws_size, hipStream_t stream)
{
    const float* node_f = (const float*)d_in[0];
    const float* msg_f  = (const float*)d_in[1];
    const int*   ei     = (const int*)d_in[2];
    const float* wsrc[12] = {
        (const float*)d_in[3],  (const float*)d_in[5],   // me_w1, me_w2
        (const float*)d_in[7],  (const float*)d_in[9],   // ne_w1, ne_w2
        (const float*)d_in[11], (const float*)d_in[12],  // c1_wl, c1_wr
        (const float*)d_in[15], (const float*)d_in[16],  // c2_wl, c2_wr
        (const float*)d_in[19], (const float*)d_in[20],  // c3_wl, c3_wr
        (const float*)d_in[23], (const float*)d_in[25],  // en_w1, en_w2
    };
    const int wsz[12] = {256*256, 128*256, 128*128, 128*128,
                         256*256, 256*256, 128*256, 128*256,
                         256*128, 256*128, 512*256, 256*512};
    const float* me_b1 = (const float*)d_in[4];
    const float* me_b2 = (const float*)d_in[6];
    const float* ne_b1 = (const float*)d_in[8];
    const float* ne_b2 = (const float*)d_in[10];
    const float* c1_at = (const float*)d_in[13];
    const float* c1_b  = (const float*)d_in[14];
    const float* c2_at = (const float*)d_in[17];
    const float* c2_b  = (const float*)d_in[18];
    const float* c3_at = (const float*)d_in[21];
    const float* c3_b  = (const float*)d_in[22];
    const float* en_b1 = (const float*)d_in[24];
    const float* en_b2 = (const float*)d_in[26];
    const float* ln_g  = (const float*)d_in[27];
    const float* ln_b  = (const float*)d_in[28];

    const int N  = in_sizes[0] / 128;   // 20000
    const int E  = in_sizes[2] / 2;     // 320000
    const int ET = E + N;

    // ---- workspace regions (each SZ = N*256*4 bytes), aggressive aliasing --
    char* base = (char*)d_ws;
    const size_t SZ = (size_t)N * 256 * 4;
    char* RA = base;            // Pm pair            -> X1 pair (conv1 out)
    char* RB = base + SZ;       // Ph1 pair -> X3 pair (conv3 out) -> EN2 f32
    char* RC = base + 2 * SZ;   // Pn pair + Pnh pair -> X2 pair (conv2 out)
    char* RD = base + 3 * SZ;   // X0 pair (encoder concat out)
    char* RE = base + 4 * SZ;   // XL f32 -> HB hi
    char* RF = base + 5 * SZ;   // XR f32 -> HB lo
    char* RG = base + 6 * SZ;   // edge buffers + weight pairs

    _Float16* Pm_h = (_Float16*)RA;  _Float16* Pm_l = Pm_h + (size_t)N * 256;
    _Float16* X1_h = (_Float16*)RA;  _Float16* X1_l = X1_h + (size_t)N * 256;
    _Float16* Ph1_h = (_Float16*)RB; _Float16* Ph1_l = Ph1_h + (size_t)N * 256;
    _Float16* X3_h = (_Float16*)RB;  _Float16* X3_l = X3_h + (size_t)N * 256;
    float*    EN2  = (float*)RB;
    _Float16* Pn_h = (_Float16*)RC;  _Float16* Pn_l = Pn_h + (size_t)N * 128;
    _Float16* Pnh_h = Pn_l + (size_t)N * 128;
    _Float16* Pnh_l = Pnh_h + (size_t)N * 128;
    _Float16* X2_h = (_Float16*)RC;  _Float16* X2_l = X2_h + (size_t)N * 128;
    _Float16* X0_h = (_Float16*)RD;  _Float16* X0_l = X0_h + (size_t)N * 256;
    float* XL = (float*)RE;
    float* XR = (float*)RF;
    _Float16* HB_h = (_Float16*)RE;  // N*512 halves
    _Float16* HB_l = (_Float16*)RF;

    float* LOG = (float*)RG;                 // ET*4 floats max
    int* CNT = (int*)(LOG + (size_t)ET * 4); // N
    int* OFF = CNT + N;                      // N+1
    int* CUR = OFF + N + 1;                  // N
    int* SRCJ = CUR + N;                     // ET
    _Float16* WP = (_Float16*)(SRCJ + ET);

    // weight pair pointers
    _Float16 *wh[12], *wl[12];
    {
        _Float16* cur = WP;
        for (int i = 0; i < 12; i++) {
            wh[i] = cur; wl[i] = cur + wsz[i]; cur += 2 * (size_t)wsz[i];
        }
    }

    const dim3 B256(256);

    // ---- fused split: 12 weights + msg + node ----
    {
        SplitArgs sa;
        int cum = 0;
        for (int i = 0; i < 12; i++) {
            sa.src[i] = wsrc[i]; sa.dh[i] = wh[i]; sa.dl[i] = wl[i];
            sa.off[i] = cum; cum += wsz[i] / 4;
        }
        sa.src[12] = msg_f;  sa.dh[12] = Pm_h; sa.dl[12] = Pm_l;
        sa.off[12] = cum; cum += N * 256 / 4;
        sa.src[13] = node_f; sa.dh[13] = Pn_h; sa.dl[13] = Pn_l;
        sa.off[13] = cum; cum += N * 128 / 4;
        sa.off[14] = cum;
        split_multi<<<ceildiv(cum, 256), B256, 0, stream>>>(sa, cum);
    }

    // ---- CSR build (shared by all three convs) ----
    fill_u32<<<ceildiv(N, 256), B256, 0, stream>>>((unsigned int*)CNT, N, 0u);
    edge_count<<<ceildiv(ET, 256), B256, 0, stream>>>(ei, E, ET, CNT);
    scan_offsets<<<1, 1024, 0, stream>>>(CNT, N, OFF, CUR);
    edge_scatter<<<ceildiv(ET, 256), B256, 0, stream>>>(ei, E, ET, CUR, SRCJ);

    const int MB_ = ceildiv(N, 128);   // GEMM grid rows (157)
    const int GGAT = ceildiv(N, 4);

    // ---- encoders -> X0 pair [N,256] = [node_emb | msg_emb] ----
    gemm_mfma<1, true ><<<dim3(4, MB_), B256, 0, stream>>>(
        Pm_h, Pm_l, wh[0], wl[0], me_b1, nullptr, Ph1_h, Ph1_l, N, 256, 256);
    gemm_mfma<1, false><<<dim3(2, MB_), B256, 0, stream>>>(
        Ph1_h, Ph1_l, wh[1], wl[1], me_b2, nullptr, X0_h + 128, X0_l + 128, N, 256, 256);
    gemm_mfma<1, true ><<<dim3(2, MB_), B256, 0, stream>>>(
        Pn_h, Pn_l, wh[2], wl[2], ne_b1, nullptr, Pnh_h, Pnh_l, N, 128, 128);
    gemm_mfma<1, false><<<dim3(2, MB_), B256, 0, stream>>>(
        Pnh_h, Pnh_l, wh[3], wl[3], ne_b2, nullptr, X0_h, X0_l, N, 128, 256);

    // ---- conv1: X0 (256) -> X1 pair (4 heads x 64, concat, relu) ----
    gemm_mfma<0, false><<<dim3(4, MB_), B256, 0, stream>>>(
        X0_h, X0_l, wh[4], wl[4], nullptr, XL, nullptr, nullptr, N, 256, 256);
    gemm_mfma<0, false><<<dim3(4, MB_), B256, 0, stream>>>(
        X0_h, X0_l, wh[5], wl[5], nullptr, XR, nullptr, nullptr, N, 256, 256);
    gat_fused<4, 64, true><<<GGAT, B256, 0, stream>>>(
        XL, XR, c1_at, c1_b, SRCJ, OFF, LOG, N, X1_h, X1_l);

    // ---- conv2: X1 (256) -> X2 pair (2 heads x 64, concat, relu) ----
    gemm_mfma<0, false><<<dim3(2, MB_), B256, 0, stream>>>(
        X1_h, X1_l, wh[6], wl[6], nullptr, XL, nullptr, nullptr, N, 256, 128);
    gemm_mfma<0, false><<<dim3(2, MB_), B256, 0, stream>>>(
        X1_h, X1_l, wh[7], wl[7], nullptr, XR, nullptr, nullptr, N, 256, 128);
    gat_fused<2, 64, true><<<GGAT, B256, 0, stream>>>(
        XL, XR, c2_at, c2_b, SRCJ, OFF, LOG, N, X2_h, X2_l);

    // ---- conv3: X2 (128) -> X3 pair (1 head x 256) ----
    gemm_mfma<0, false><<<dim3(4, MB_), B256, 0, stream>>>(
        X2_h, X2_l, wh[8], wl[8], nullptr, XL, nullptr, nullptr, N, 128, 256);
    gemm_mfma<0, false><<<dim3(4, MB_), B256, 0, stream>>>(
        X2_h, X2_l, wh[9], wl[9], nullptr, XR, nullptr, nullptr, N, 128, 256);
    gat_fused<1, 256, false><<<GGAT, B256, 0, stream>>>(
        XL, XR, c3_at, c3_b, SRCJ, OFF, LOG, N, X3_h, X3_l);

    // ---- enhancer: X3 -> HB pair (512, relu) -> EN2 f32 -> LN -> d_out ----
    gemm_mfma<1, true ><<<dim3(8, MB_), B256, 0, stream>>>(
        X3_h, X3_l, wh[10], wl[10], en_b1, nullptr, HB_h, HB_l, N, 256, 512);
    gemm_mfma<0, false><<<dim3(4, MB_), B256, 0, stream>>>(
        HB_h, HB_l, wh[11], wl[11], en_b2, EN2, nullptr, nullptr, N, 512, 256);
    layernorm256<<<ceildiv(N, 4), B256, 0, stream>>>(EN2, ln_g, ln_b, (float*)d_out, N);
}

// Round 6
// 609.319 us; speedup vs baseline: 1.6061x; 1.2156x over previous
//
#include <hip/hip_runtime.h>
#include <math.h>

// ---------------------------------------------------------------------------
// StrategicGNN forward: MLP encoders -> 3x GATv2 -> MLP enhancer -> LayerNorm
// GEMMs: fp16x3-split MFMA (Ah*Wh + Ah*Wl + Al*Wh), global_load_lds staging.
// Conv projections emit fp16 [xl|xr]; GAT = one-pass online-softmax per dst.
// ---------------------------------------------------------------------------

static inline int ceildiv(int a, int b) { return (a + b - 1) / b; }

typedef _Float16 h8  __attribute__((ext_vector_type(8)));
typedef _Float16 h4v __attribute__((ext_vector_type(4)));
typedef _Float16 h2v __attribute__((ext_vector_type(2)));
typedef float    f4x __attribute__((ext_vector_type(4)));

__device__ __forceinline__ void gload16(const _Float16* g, _Float16* l) {
    __builtin_amdgcn_global_load_lds(
        (const __attribute__((address_space(1))) void*)g,
        (__attribute__((address_space(3))) void*)l, 16, 0, 0);
}

// ---- small utility ---------------------------------------------------------
__global__ void fill_u32(unsigned int* __restrict__ p, int n, unsigned int v) {
    int i = blockIdx.x * blockDim.x + threadIdx.x;
    if (i < n) p[i] = v;
}

// ---- fused hi/lo split of raw inputs + all weight matrices -----------------
struct SplitArgs {
    const float* src[14];
    _Float16* dh[14];
    _Float16* dl[14];
    int off[15];          // prefix sums, float4 units
};

__global__ void split_multi(SplitArgs a, int totalv) {
    int v = blockIdx.x * blockDim.x + threadIdx.x;
    if (v >= totalv) return;
    int s = 0;
#pragma unroll
    for (int i = 1; i < 14; i++) s += (v >= a.off[i]);
    int lv = v - a.off[s];
    float4 f = ((const float4*)a.src[s])[lv];
    float vals[4] = {f.x, f.y, f.z, f.w};
    h4v hh, hl;
#pragma unroll
    for (int j = 0; j < 4; j++) {
        _Float16 h = (_Float16)vals[j];
        hh[j] = h;
        hl[j] = (_Float16)(vals[j] - (float)h);
    }
    *(h4v*)(a.dh[s] + (size_t)lv * 4) = hh;
    *(h4v*)(a.dl[s] + (size_t)lv * 4) = hl;
}

// ---- MFMA GEMM: C[M,*] = act(A[M,K] @ W[*,K]^T + bias) ---------------------
// Tile 128x64, BK=64, 4 waves (64x32 each). A,W staged via global_load_lds
// (linear LDS dest) with inverse-XOR-swizzled global source; reads apply the
// same 16B-chunk XOR (involution) -> bank-conflict-free ds_read_b128.
// OUT 0: fp32 Cf. OUT 1: fp16 hi/lo pair Chi/Clo. OUT 2: fp16 single Chi.
template <int OUT, bool RELU>
__global__ __launch_bounds__(256) void gemm_mfma(
    const _Float16* __restrict__ Ahi, const _Float16* __restrict__ Alo,
    const _Float16* __restrict__ Whi, const _Float16* __restrict__ Wlo,
    const float* __restrict__ bias, float* __restrict__ Cf,
    _Float16* __restrict__ Chi, _Float16* __restrict__ Clo,
    int M, int K, int ldc)
{
    __shared__ _Float16 sA[2][128][64];   // [hi/lo][row][k]
    __shared__ _Float16 sW[2][64][64];
    const int t = threadIdx.x;
    const int lane = t & 63;
    const int w = t >> 6, wr = w >> 1, wc = w & 1;   // 2x2 waves of 64x32
    const int m0 = blockIdx.y * 128, n0 = blockIdx.x * 64;

    f4x acc[4][2] = {};

    for (int k0 = 0; k0 < K; k0 += 64) {
        // A tile: v = bv + lane; row = v>>3, lds chunk = lane&7 (linear dest);
        // global source chunk = (lane&7) ^ (row&7)  [involution]
#pragma unroll
        for (int i = 0; i < 4; i++) {
            const int bv = w * 64 + i * 256;          // wave-uniform
            const int row = (bv >> 3) + (lane >> 3);
            const int c8 = (lane & 7) ^ (row & 7);
            int gr = m0 + row; if (gr > M - 1) gr = M - 1;   // clamp tail
            const size_t g = (size_t)gr * K + k0 + c8 * 8;
            gload16(Ahi + g, &sA[0][0][0] + (size_t)bv * 8);
            gload16(Alo + g, &sA[1][0][0] + (size_t)bv * 8);
        }
#pragma unroll
        for (int i = 0; i < 2; i++) {
            const int bv = w * 64 + i * 256;
            const int row = (bv >> 3) + (lane >> 3);
            const int c8 = (lane & 7) ^ (row & 7);
            const size_t g = (size_t)(n0 + row) * K + k0 + c8 * 8;
            gload16(Whi + g, &sW[0][0][0] + (size_t)bv * 8);
            gload16(Wlo + g, &sW[1][0][0] + (size_t)bv * 8);
        }
        __syncthreads();                 // drains vmcnt (m97 pattern)
#pragma unroll
        for (int ks = 0; ks < 2; ks++) {        // two K=32 slices per BK=64
            const int kg = ks * 4 + (lane >> 4);   // 16B chunk index along k
            h8 afh[4], afl[4], wfh[2], wfl[2];
#pragma unroll
            for (int mi = 0; mi < 4; mi++) {
                int row = wr * 64 + mi * 16 + (lane & 15);
                int cs = ((kg ^ (row & 7)) << 3);
                afh[mi] = *(const h8*)&sA[0][row][cs];
                afl[mi] = *(const h8*)&sA[1][row][cs];
            }
#pragma unroll
            for (int ni = 0; ni < 2; ni++) {
                int row = wc * 32 + ni * 16 + (lane & 15);
                int cs = ((kg ^ (row & 7)) << 3);
                wfh[ni] = *(const h8*)&sW[0][row][cs];
                wfl[ni] = *(const h8*)&sW[1][row][cs];
            }
#pragma unroll
            for (int mi = 0; mi < 4; mi++)
#pragma unroll
                for (int ni = 0; ni < 2; ni++) {
                    acc[mi][ni] = __builtin_amdgcn_mfma_f32_16x16x32_f16(
                        afh[mi], wfh[ni], acc[mi][ni], 0, 0, 0);
                    acc[mi][ni] = __builtin_amdgcn_mfma_f32_16x16x32_f16(
                        afh[mi], wfl[ni], acc[mi][ni], 0, 0, 0);
                    acc[mi][ni] = __builtin_amdgcn_mfma_f32_16x16x32_f16(
                        afl[mi], wfh[ni], acc[mi][ni], 0, 0, 0);
                }
        }
        __syncthreads();
    }
    // epilogue: C/D layout col=lane&15, row=(lane>>4)*4+reg  [m89-verified]
#pragma unroll
    for (int mi = 0; mi < 4; mi++) {
#pragma unroll
        for (int ni = 0; ni < 2; ni++) {
            int col = n0 + wc * 32 + ni * 16 + (lane & 15);
            float bz = bias ? bias[col] : 0.f;
#pragma unroll
            for (int r = 0; r < 4; r++) {
                int grow = m0 + wr * 64 + mi * 16 + (lane >> 4) * 4 + r;
                if (grow < M) {
                    float vv = acc[mi][ni][r] + bz;
                    if (RELU) vv = fmaxf(vv, 0.f);
                    if (OUT == 0) {
                        Cf[(size_t)grow * ldc + col] = vv;
                    } else if (OUT == 1) {
                        _Float16 h = (_Float16)vv;
                        Chi[(size_t)grow * ldc + col] = h;
                        Clo[(size_t)grow * ldc + col] = (_Float16)(vv - (float)h);
                    } else {
                        Chi[(size_t)grow * ldc + col] = (_Float16)vv;
                    }
                }
            }
        }
    }
}

// ---- CSR build (dst-sorted incidence; self-loop e in [E, E+N) ) ------------
__global__ void edge_count(const int* __restrict__ ei, int E, int ET,
                           int* __restrict__ cnt) {
    int e = blockIdx.x * blockDim.x + threadIdx.x;
    if (e >= ET) return;
    int dst = (e < E) ? ei[E + e] : e - E;
    atomicAdd(&cnt[dst], 1);
}

__global__ __launch_bounds__(1024) void scan_offsets(
    const int* __restrict__ cnt, int n, int* __restrict__ off,
    int* __restrict__ cur)
{
    __shared__ int s[1024];
    const int t = threadIdx.x;
    const int CH = (n + 1023) / 1024;
    int base = t * CH;
    int local[32];
    int sum = 0;
    for (int j = 0; j < CH; j++) {
        int idx = base + j;
        int v = (idx < n) ? cnt[idx] : 0;
        local[j] = sum;
        sum += v;
    }
    s[t] = sum;
    __syncthreads();
    for (int d = 1; d < 1024; d <<= 1) {
        int v = (t >= d) ? s[t - d] : 0;
        __syncthreads();
        s[t] += v;
        __syncthreads();
    }
    int excl = s[t] - sum;
    for (int j = 0; j < CH; j++) {
        int idx = base + j;
        if (idx < n) { off[idx] = excl + local[j]; cur[idx] = excl + local[j]; }
    }
    if (t == 1023) off[n] = s[1023];
}

// scatter src ids into dst-sorted CSR order
__global__ void edge_scatter(const int* __restrict__ ei, int E, int ET,
                             int* __restrict__ cur, int* __restrict__ srcj) {
    int e = blockIdx.x * blockDim.x + threadIdx.x;
    if (e >= ET) return;
    int dst, src;
    if (e < E) { dst = ei[E + e]; src = ei[e]; } else { dst = src = e - E; }
    int pos = atomicAdd(&cur[dst], 1);
    srcj[pos] = src;
}

// ---- fused GATv2 layer: wave per dst node, ONE pass (online softmax) -------
// xlr = fp16 [Nn, 2*H*C] = [xl | xr]. Feature->lane map: c = lane*R + r.
// Per edge: gather xl[src] (fp16), logit via group shuffle-reduce, then
// flash-style rescale of running (m, denom, acc). Output fp16 hi/lo pair.
template <int H, int C, bool RELU>
__global__ __launch_bounds__(256) void gat_fused(
    const _Float16* __restrict__ xlr,
    const float* __restrict__ att, const float* __restrict__ bias,
    const int* __restrict__ srcj, const int* __restrict__ off, int Nn,
    _Float16* __restrict__ oh, _Float16* __restrict__ ol)
{
    constexpr int HC = H * C;
    constexpr int LD = 2 * HC;
    constexpr int R = HC / 64;                    // floats per lane (2 or 4)
    constexpr int G = C / R;                      // lanes per head group
    const int wave = threadIdx.x >> 6;
    const int lane = threadIdx.x & 63;
    const int i = blockIdx.x * 4 + wave;
    if (i >= Nn) return;
    const int j0 = off[i], j1 = off[i + 1];

    float xrv[R], attv[R];
#pragma unroll
    for (int r = 0; r < R; r++) {
        int c = lane * R + r;
        xrv[r] = (float)xlr[(size_t)i * LD + HC + c];
        attv[r] = att[c];
    }

    float m = -INFINITY, sden = 0.f, acc[R] = {};

    auto LOADX = [&](int s, float* xv) {
        const _Float16* p = xlr + (size_t)s * LD + (size_t)lane * R;
        if constexpr (R == 4) {
            h4v hv = *(const h4v*)p;
            xv[0] = (float)hv[0]; xv[1] = (float)hv[1];
            xv[2] = (float)hv[2]; xv[3] = (float)hv[3];
        } else {
            h2v hv = *(const h2v*)p;
            xv[0] = (float)hv[0]; xv[1] = (float)hv[1];
        }
    };

    float xv[R];
    LOADX(srcj[j0], xv);
    for (int j = j0; j < j1; j++) {
        float xn[R] = {};
        if (j + 1 < j1) LOADX(srcj[j + 1], xn);   // prefetch next gather
        float dot = 0.f;
#pragma unroll
        for (int r = 0; r < R; r++) {
            float v = xv[r] + xrv[r];
            v = v > 0.f ? v : 0.2f * v;           // leaky_relu(., 0.2)
            dot += v * attv[r];
        }
#pragma unroll
        for (int d = 1; d < G; d <<= 1) dot += __shfl_xor(dot, d);
        float mn = fmaxf(m, dot);
        float sc = expf(m - mn);                  // 0 on first iteration
        float p  = expf(dot - mn);
        sden = sden * sc + p;
#pragma unroll
        for (int r = 0; r < R; r++) acc[r] = acc[r] * sc + p * xv[r];
        m = mn;
#pragma unroll
        for (int r = 0; r < R; r++) xv[r] = xn[r];
    }

    const float rd = 1.f / sden;
#pragma unroll
    for (int r = 0; r < R; r++) {
        int c = lane * R + r;
        float v = acc[r] * rd + bias[c];
        if (RELU) v = fmaxf(v, 0.f);
        _Float16 h = (_Float16)v;
        oh[(size_t)i * HC + c] = h;
        ol[(size_t)i * HC + c] = (_Float16)(v - (float)h);
    }
}

// ---- LayerNorm over 256 features: wave per row -----------------------------
__global__ __launch_bounds__(256) void layernorm256(
    const float* __restrict__ x, const float* __restrict__ g,
    const float* __restrict__ b, float* __restrict__ out, int Nn)
{
    const int wave = threadIdx.x >> 6;
    const int lane = threadIdx.x & 63;
    const int i = blockIdx.x * 4 + wave;
    if (i >= Nn) return;
    float v[4];
    float sum = 0.f;
#pragma unroll
    for (int r = 0; r < 4; r++) {
        v[r] = x[(size_t)i * 256 + r * 64 + lane];
        sum += v[r];
    }
#pragma unroll
    for (int off = 32; off >= 1; off >>= 1) sum += __shfl_xor(sum, off);
    float mu = sum * (1.f / 256.f);
    float s2 = 0.f;
#pragma unroll
    for (int r = 0; r < 4; r++) { float d = v[r] - mu; s2 += d * d; }
#pragma unroll
    for (int off = 32; off >= 1; off >>= 1) s2 += __shfl_xor(s2, off);
    float rstd = 1.f / sqrtf(s2 * (1.f / 256.f) + 1e-5f);
#pragma unroll
    for (int r = 0; r < 4; r++) {
        int c = r * 64 + lane;
        out[(size_t)i * 256 + c] = (v[r] - mu) * rstd * g[c] + b[c];
    }
}

// ---------------------------------------------------------------------------
extern "C" void kernel_launch(void* const* d_in, const int* in_sizes, int n_in,
                              void* d_out, int out_size, void* d_ws,
                              size_t ws_size, hipStream_t stream)
{
    const float* node_f = (const float*)d_in[0];
    const float* msg_f  = (const float*)d_in[1];
    const int*   ei     = (const int*)d_in[2];
    const float* wsrc[12] = {
        (const float*)d_in[3],  (const float*)d_in[5],   // me_w1, me_w2
        (const float*)d_in[7],  (const float*)d_in[9],   // ne_w1, ne_w2
        (const float*)d_in[11], (const float*)d_in[12],  // c1_wl, c1_wr
        (const float*)d_in[15], (const float*)d_in[16],  // c2_wl, c2_wr
        (const float*)d_in[19], (const float*)d_in[20],  // c3_wl, c3_wr
        (const float*)d_in[23], (const float*)d_in[25],  // en_w1, en_w2
    };
    const int wsz[12] = {256*256, 128*256, 128*128, 128*128,
                         256*256, 256*256, 128*256, 128*256,
                         256*128, 256*128, 512*256, 256*512};
    const float* me_b1 = (const float*)d_in[4];
    const float* me_b2 = (const float*)d_in[6];
    const float* ne_b1 = (const float*)d_in[8];
    const float* ne_b2 = (const float*)d_in[10];
    const float* c1_at = (const float*)d_in[13];
    const float* c1_b  = (const float*)d_in[14];
    const float* c2_at = (const float*)d_in[17];
    const float* c2_b  = (const float*)d_in[18];
    const float* c3_at = (const float*)d_in[21];
    const float* c3_b  = (const float*)d_in[22];
    const float* en_b1 = (const float*)d_in[24];
    const float* en_b2 = (const float*)d_in[26];
    const float* ln_g  = (const float*)d_in[27];
    const float* ln_b  = (const float*)d_in[28];

    const int N  = in_sizes[0] / 128;   // 20000
    const int E  = in_sizes[2] / 2;     // 320000
    const int ET = E + N;

    // ---- workspace regions (each SZ = N*256*4 bytes) ----
    char* base = (char*)d_ws;
    const size_t SZ = (size_t)N * 256 * 4;
    char* RA = base;            // Pm pair            -> X1 pair (conv1 out)
    char* RB = base + SZ;       // Ph1 pair -> X3 pair (conv3 out) -> EN2 f32
    char* RC = base + 2 * SZ;   // Pn pair + Pnh pair -> X2 pair (conv2 out)
    char* RD = base + 3 * SZ;   // X0 pair (encoder concat out)
    char* RE = base + 4 * SZ;   // XLR fp16 (conv proj out) -> HB hi
    char* RF = base + 5 * SZ;   // HB lo
    char* RG = base + 6 * SZ;   // CSR ints + weight pairs

    _Float16* Pm_h = (_Float16*)RA;  _Float16* Pm_l = Pm_h + (size_t)N * 256;
    _Float16* X1_h = (_Float16*)RA;  _Float16* X1_l = X1_h + (size_t)N * 256;
    _Float16* Ph1_h = (_Float16*)RB; _Float16* Ph1_l = Ph1_h + (size_t)N * 256;
    _Float16* X3_h = (_Float16*)RB;  _Float16* X3_l = X3_h + (size_t)N * 256;
    float*    EN2  = (float*)RB;
    _Float16* Pn_h = (_Float16*)RC;  _Float16* Pn_l = Pn_h + (size_t)N * 128;
    _Float16* Pnh_h = Pn_l + (size_t)N * 128;
    _Float16* Pnh_l = Pnh_h + (size_t)N * 128;
    _Float16* X2_h = (_Float16*)RC;  _Float16* X2_l = X2_h + (size_t)N * 128;
    _Float16* X0_h = (_Float16*)RD;  _Float16* X0_l = X0_h + (size_t)N * 256;
    _Float16* XLR  = (_Float16*)RE;  // N x 512 max, fp16 [xl|xr]
    _Float16* HB_h = (_Float16*)RE;  // N x 512 halves
    _Float16* HB_l = (_Float16*)RF;

    int* CNT = (int*)RG;                     // N
    int* OFF = CNT + N;                      // N+1
    int* CUR = OFF + N + 1;                  // N
    int* SRCJ = CUR + N;                     // ET
    _Float16* WP = (_Float16*)(SRCJ + ET);

    // weight pair pointers; conv pairs stacked so [wl;wr] is one matrix
    _Float16 *wh[12], *wl[12];
    {
        _Float16* cur = WP;
        auto pair = [&](int i) { wh[i] = cur; cur += wsz[i]; wl[i] = cur; cur += wsz[i]; };
        pair(0); pair(1); pair(2); pair(3);
        auto stacked = [&](int i) {
            wh[i] = cur; wh[i+1] = cur + wsz[i]; cur += 2 * (size_t)wsz[i];
            wl[i] = cur; wl[i+1] = cur + wsz[i]; cur += 2 * (size_t)wsz[i];
        };
        stacked(4); stacked(6); stacked(8);
        pair(10); pair(11);
    }

    const dim3 B256(256);

    // ---- fused split: 12 weights + msg + node ----
    {
        SplitArgs sa;
        int cum = 0;
        for (int i = 0; i < 12; i++) {
            sa.src[i] = wsrc[i]; sa.dh[i] = wh[i]; sa.dl[i] = wl[i];
            sa.off[i] = cum; cum += wsz[i] / 4;
        }
        sa.src[12] = msg_f;  sa.dh[12] = Pm_h; sa.dl[12] = Pm_l;
        sa.off[12] = cum; cum += N * 256 / 4;
        sa.src[13] = node_f; sa.dh[13] = Pn_h; sa.dl[13] = Pn_l;
        sa.off[13] = cum; cum += N * 128 / 4;
        sa.off[14] = cum;
        split_multi<<<ceildiv(cum, 256), B256, 0, stream>>>(sa, cum);
    }

    // ---- CSR build (shared by all three convs) ----
    fill_u32<<<ceildiv(N, 256), B256, 0, stream>>>((unsigned int*)CNT, N, 0u);
    edge_count<<<ceildiv(ET, 256), B256, 0, stream>>>(ei, E, ET, CNT);
    scan_offsets<<<1, 1024, 0, stream>>>(CNT, N, OFF, CUR);
    edge_scatter<<<ceildiv(ET, 256), B256, 0, stream>>>(ei, E, ET, CUR, SRCJ);

    const int MB_ = ceildiv(N, 128);   // 157
    const int GGAT = ceildiv(N, 4);

    // ---- encoders -> X0 pair [N,256] = [node_emb | msg_emb] ----
    gemm_mfma<1, true ><<<dim3(4, MB_), B256, 0, stream>>>(
        Pm_h, Pm_l, wh[0], wl[0], me_b1, nullptr, Ph1_h, Ph1_l, N, 256, 256);
    gemm_mfma<1, false><<<dim3(2, MB_), B256, 0, stream>>>(
        Ph1_h, Ph1_l, wh[1], wl[1], me_b2, nullptr, X0_h + 128, X0_l + 128, N, 256, 256);
    gemm_mfma<1, true ><<<dim3(2, MB_), B256, 0, stream>>>(
        Pn_h, Pn_l, wh[2], wl[2], ne_b1, nullptr, Pnh_h, Pnh_l, N, 128, 128);
    gemm_mfma<1, false><<<dim3(2, MB_), B256, 0, stream>>>(
        Pnh_h, Pnh_l, wh[3], wl[3], ne_b2, nullptr, X0_h, X0_l, N, 128, 256);

    // ---- conv1: proj (512 cols fp16 [xl|xr]) + fused GAT ----
    gemm_mfma<2, false><<<dim3(8, MB_), B256, 0, stream>>>(
        X0_h, X0_l, wh[4], wl[4], nullptr, nullptr, XLR, nullptr, N, 256, 512);
    gat_fused<4, 64, true><<<GGAT, B256, 0, stream>>>(
        XLR, c1_at, c1_b, SRCJ, OFF, N, X1_h, X1_l);

    // ---- conv2: proj (256 cols) + fused GAT ----
    gemm_mfma<2, false><<<dim3(4, MB_), B256, 0, stream>>>(
        X1_h, X1_l, wh[6], wl[6], nullptr, nullptr, XLR, nullptr, N, 256, 256);
    gat_fused<2, 64, true><<<GGAT, B256, 0, stream>>>(
        XLR, c2_at, c2_b, SRCJ, OFF, N, X2_h, X2_l);

    // ---- conv3: proj (512 cols, K=128) + fused GAT ----
    gemm_mfma<2, false><<<dim3(8, MB_), B256, 0, stream>>>(
        X2_h, X2_l, wh[8], wl[8], nullptr, nullptr, XLR, nullptr, N, 128, 512);
    gat_fused<1, 256, false><<<GGAT, B256, 0, stream>>>(
        XLR, c3_at, c3_b, SRCJ, OFF, N, X3_h, X3_l);

    // ---- enhancer: X3 -> HB pair (512, relu) -> EN2 f32 -> LN -> d_out ----
    gemm_mfma<1, true ><<<dim3(8, MB_), B256, 0, stream>>>(
        X3_h, X3_l, wh[10], wl[10], en_b1, nullptr, HB_h, HB_l, N, 256, 512);
    gemm_mfma<0, false><<<dim3(4, MB_), B256, 0, stream>>>(
        HB_h, HB_l, wh[11], wl[11], en_b2, EN2, nullptr, nullptr, N, 512, 256);
    layernorm256<<<ceildiv(N, 4), B256, 0, stream>>>(EN2, ln_g, ln_b, (float*)d_out, N);
}

// Round 9
// 582.705 us; speedup vs baseline: 1.6794x; 1.0457x over previous
//
#include <hip/hip_runtime.h>
#include <math.h>

// ---------------------------------------------------------------------------
// StrategicGNN forward: MLP encoders -> 3x GATv2 -> MLP enhancer -> LayerNorm
// GEMMs: fp16x3-split MFMA (Ah*Wh + Ah*Wl + Al*Wh), global_load_lds staging.
// GAT: one-pass online-softmax per dst, packed-fp16 logits (fdot2), log2-
// domain defer-max (single exp2 on the common path).
// ---------------------------------------------------------------------------

static inline int ceildiv(int a, int b) { return (a + b - 1) / b; }

typedef _Float16 h8  __attribute__((ext_vector_type(8)));
typedef _Float16 h4v __attribute__((ext_vector_type(4)));
typedef _Float16 h2v __attribute__((ext_vector_type(2)));
typedef float    f4x __attribute__((ext_vector_type(4)));

__device__ __forceinline__ void gload16(const _Float16* g, _Float16* l) {
    __builtin_amdgcn_global_load_lds(
        (const __attribute__((address_space(1))) void*)g,
        (__attribute__((address_space(3))) void*)l, 16, 0, 0);
}

// ---- small utility ---------------------------------------------------------
__global__ void fill_u32(unsigned int* __restrict__ p, int n, unsigned int v) {
    int i = blockIdx.x * blockDim.x + threadIdx.x;
    if (i < n) p[i] = v;
}

// ---- fused hi/lo split of raw inputs + all weight matrices -----------------
struct SplitArgs {
    const float* src[14];
    _Float16* dh[14];
    _Float16* dl[14];
    int off[15];          // prefix sums, float4 units
};

__global__ void split_multi(SplitArgs a, int totalv) {
    int v = blockIdx.x * blockDim.x + threadIdx.x;
    if (v >= totalv) return;
    int s = 0;
#pragma unroll
    for (int i = 1; i < 14; i++) s += (v >= a.off[i]);
    int lv = v - a.off[s];
    float4 f = ((const float4*)a.src[s])[lv];
    float vals[4] = {f.x, f.y, f.z, f.w};
    h4v hh, hl;
#pragma unroll
    for (int j = 0; j < 4; j++) {
        _Float16 h = (_Float16)vals[j];
        hh[j] = h;
        hl[j] = (_Float16)(vals[j] - (float)h);
    }
    *(h4v*)(a.dh[s] + (size_t)lv * 4) = hh;
    *(h4v*)(a.dl[s] + (size_t)lv * 4) = hl;
}

// ---- MFMA GEMM: C[M,*] = act(A[M,K] @ W[*,K]^T + bias) ---------------------
// Tile 128x64, BK=64, 4 waves (64x32 each). A,W staged via global_load_lds
// (linear LDS dest) with inverse-XOR-swizzled global source; reads apply the
// same 16B-chunk XOR (involution) -> bank-conflict-free ds_read_b128.
// OUT 0: fp32 Cf. OUT 1: fp16 hi/lo pair Chi/Clo. OUT 2: fp16 single Chi.
template <int OUT, bool RELU>
__global__ __launch_bounds__(256) void gemm_mfma(
    const _Float16* __restrict__ Ahi, const _Float16* __restrict__ Alo,
    const _Float16* __restrict__ Whi, const _Float16* __restrict__ Wlo,
    const float* __restrict__ bias, float* __restrict__ Cf,
    _Float16* __restrict__ Chi, _Float16* __restrict__ Clo,
    int M, int K, int ldc)
{
    __shared__ _Float16 sA[2][128][64];   // [hi/lo][row][k]
    __shared__ _Float16 sW[2][64][64];
    const int t = threadIdx.x;
    const int lane = t & 63;
    const int w = t >> 6, wr = w >> 1, wc = w & 1;   // 2x2 waves of 64x32
    const int m0 = blockIdx.y * 128, n0 = blockIdx.x * 64;

    f4x acc[4][2] = {};

    for (int k0 = 0; k0 < K; k0 += 64) {
        // A tile: v = bv + lane; row = v>>3, lds chunk = lane&7 (linear dest);
        // global source chunk = (lane&7) ^ (row&7)  [involution]
#pragma unroll
        for (int i = 0; i < 4; i++) {
            const int bv = w * 64 + i * 256;          // wave-uniform
            const int row = (bv >> 3) + (lane >> 3);
            const int c8 = (lane & 7) ^ (row & 7);
            int gr = m0 + row; if (gr > M - 1) gr = M - 1;   // clamp tail
            const size_t g = (size_t)gr * K + k0 + c8 * 8;
            gload16(Ahi + g, &sA[0][0][0] + (size_t)bv * 8);
            gload16(Alo + g, &sA[1][0][0] + (size_t)bv * 8);
        }
#pragma unroll
        for (int i = 0; i < 2; i++) {
            const int bv = w * 64 + i * 256;
            const int row = (bv >> 3) + (lane >> 3);
            const int c8 = (lane & 7) ^ (row & 7);
            const size_t g = (size_t)(n0 + row) * K + k0 + c8 * 8;
            gload16(Whi + g, &sW[0][0][0] + (size_t)bv * 8);
            gload16(Wlo + g, &sW[1][0][0] + (size_t)bv * 8);
        }
        __syncthreads();                 // drains vmcnt (m97 pattern)
#pragma unroll
        for (int ks = 0; ks < 2; ks++) {        // two K=32 slices per BK=64
            const int kg = ks * 4 + (lane >> 4);   // 16B chunk index along k
            h8 afh[4], afl[4], wfh[2], wfl[2];
#pragma unroll
            for (int mi = 0; mi < 4; mi++) {
                int row = wr * 64 + mi * 16 + (lane & 15);
                int cs = ((kg ^ (row & 7)) << 3);
                afh[mi] = *(const h8*)&sA[0][row][cs];
                afl[mi] = *(const h8*)&sA[1][row][cs];
            }
#pragma unroll
            for (int ni = 0; ni < 2; ni++) {
                int row = wc * 32 + ni * 16 + (lane & 15);
                int cs = ((kg ^ (row & 7)) << 3);
                wfh[ni] = *(const h8*)&sW[0][row][cs];
                wfl[ni] = *(const h8*)&sW[1][row][cs];
            }
#pragma unroll
            for (int mi = 0; mi < 4; mi++)
#pragma unroll
                for (int ni = 0; ni < 2; ni++) {
                    acc[mi][ni] = __builtin_amdgcn_mfma_f32_16x16x32_f16(
                        afh[mi], wfh[ni], acc[mi][ni], 0, 0, 0);
                    acc[mi][ni] = __builtin_amdgcn_mfma_f32_16x16x32_f16(
                        afh[mi], wfl[ni], acc[mi][ni], 0, 0, 0);
                    acc[mi][ni] = __builtin_amdgcn_mfma_f32_16x16x32_f16(
                        afl[mi], wfh[ni], acc[mi][ni], 0, 0, 0);
                }
        }
        __syncthreads();
    }
    // epilogue: C/D layout col=lane&15, row=(lane>>4)*4+reg  [m89-verified]
#pragma unroll
    for (int mi = 0; mi < 4; mi++) {
#pragma unroll
        for (int ni = 0; ni < 2; ni++) {
            int col = n0 + wc * 32 + ni * 16 + (lane & 15);
            float bz = bias ? bias[col] : 0.f;
#pragma unroll
            for (int r = 0; r < 4; r++) {
                int grow = m0 + wr * 64 + mi * 16 + (lane >> 4) * 4 + r;
                if (grow < M) {
                    float vv = acc[mi][ni][r] + bz;
                    if (RELU) vv = fmaxf(vv, 0.f);
                    if (OUT == 0) {
                        Cf[(size_t)grow * ldc + col] = vv;
                    } else if (OUT == 1) {
                        _Float16 h = (_Float16)vv;
                        Chi[(size_t)grow * ldc + col] = h;
                        Clo[(size_t)grow * ldc + col] = (_Float16)(vv - (float)h);
                    } else {
                        Chi[(size_t)grow * ldc + col] = (_Float16)vv;
                    }
                }
            }
        }
    }
}

// ---- CSR build (dst-sorted incidence; self-loop e in [E, E+N) ) ------------
__global__ void edge_count(const int* __restrict__ ei, int E, int ET,
                           int* __restrict__ cnt) {
    int e = blockIdx.x * blockDim.x + threadIdx.x;
    if (e >= ET) return;
    int dst = (e < E) ? ei[E + e] : e - E;
    atomicAdd(&cnt[dst], 1);
}

__global__ __launch_bounds__(1024) void scan_offsets(
    const int* __restrict__ cnt, int n, int* __restrict__ off,
    int* __restrict__ cur)
{
    __shared__ int s[1024];
    const int t = threadIdx.x;
    const int CH = (n + 1023) / 1024;
    int base = t * CH;
    int local[32];
    int sum = 0;
    for (int j = 0; j < CH; j++) {
        int idx = base + j;
        int v = (idx < n) ? cnt[idx] : 0;
        local[j] = sum;
        sum += v;
    }
    s[t] = sum;
    __syncthreads();
    for (int d = 1; d < 1024; d <<= 1) {
        int v = (t >= d) ? s[t - d] : 0;
        __syncthreads();
        s[t] += v;
        __syncthreads();
    }
    int excl = s[t] - sum;
    for (int j = 0; j < CH; j++) {
        int idx = base + j;
        if (idx < n) { off[idx] = excl + local[j]; cur[idx] = excl + local[j]; }
    }
    if (t == 1023) off[n] = s[1023];
}

// scatter src ids into dst-sorted CSR order
__global__ void edge_scatter(const int* __restrict__ ei, int E, int ET,
                             int* __restrict__ cur, int* __restrict__ srcj) {
    int e = blockIdx.x * blockDim.x + threadIdx.x;
    if (e >= ET) return;
    int dst, src;
    if (e < E) { dst = ei[E + e]; src = ei[e]; } else { dst = src = e - E; }
    int pos = atomicAdd(&cur[dst], 1);
    srcj[pos] = src;
}

// ---- fused GATv2 layer: wave per dst node, ONE pass (online softmax) -------
// xlr = fp16 [Nn, 2*H*C] = [xl | xr]. Feature->lane map: c = lane*R + r.
// Per edge: packed-fp16 add/leaky + fdot2 logit, group shuffle-reduce,
// log2-domain defer-max (rescale only when max grows by >12), single exp2
// on the common path. Output fp16 hi/lo pair.
template <int H, int C, bool RELU>
__global__ __launch_bounds__(256) void gat_fused(
    const _Float16* __restrict__ xlr,
    const float* __restrict__ att, const float* __restrict__ bias,
    const int* __restrict__ srcj, const int* __restrict__ off, int Nn,
    _Float16* __restrict__ oh, _Float16* __restrict__ ol)
{
    constexpr int HC = H * C;
    constexpr int LD = 2 * HC;
    constexpr int R = HC / 64;                    // fp16 feats per lane (2/4)
    constexpr int W2 = R / 2;                     // h2v words per lane
    constexpr int G = C / R;                      // lanes per head group
    constexpr float L2E = 1.44269504088896f;
    constexpr float THR = 12.0f;                  // defer-max threshold (log2)
    const int wave = threadIdx.x >> 6;
    const int lane = threadIdx.x & 63;
    const int i = blockIdx.x * 4 + wave;
    if (i >= Nn) return;
    const int j0 = off[i], j1 = off[i + 1];

    h2v xr2[W2], at2[W2];
#pragma unroll
    for (int w2 = 0; w2 < W2; w2++) {
        int c = lane * R + 2 * w2;
        xr2[w2] = *(const h2v*)(xlr + (size_t)i * LD + HC + c);
        h2v a; a[0] = (_Float16)att[c]; a[1] = (_Float16)att[c + 1];
        at2[w2] = a;
    }

    float m2 = -INFINITY, sden = 0.f, acc[R] = {};

    auto LOADX = [&](int s, h2v* xv) {
        const _Float16* p = xlr + (size_t)s * LD + (size_t)lane * R;
        if constexpr (W2 == 2) {
            h4v hv = *(const h4v*)p;
            h2v a, b; a[0] = hv[0]; a[1] = hv[1]; b[0] = hv[2]; b[1] = hv[3];
            xv[0] = a; xv[1] = b;
        } else {
            xv[0] = *(const h2v*)p;
        }
    };

    h2v xv[W2];
    LOADX(srcj[j0], xv);
    for (int j = j0; j < j1; j++) {
        h2v xn[W2];
#pragma unroll
        for (int w2 = 0; w2 < W2; w2++) { h2v z = {0, 0}; xn[w2] = z; }
        if (j + 1 < j1) LOADX(srcj[j + 1], xn);   // prefetch next gather

        float dot = 0.f;
#pragma unroll
        for (int w2 = 0; w2 < W2; w2++) {
            h2v v = xv[w2] + xr2[w2];
            h2v s5 = v * (_Float16)0.2f;
            h2v lk;
            lk[0] = v[0] > (_Float16)0 ? v[0] : s5[0];
            lk[1] = v[1] > (_Float16)0 ? v[1] : s5[1];
            dot = __builtin_amdgcn_fdot2(lk, at2[w2], dot, false);
        }
#pragma unroll
        for (int d = 1; d < G; d <<= 1) dot += __shfl_xor(dot, d);
        float l2 = dot * L2E;

        if (l2 - m2 > THR) {                      // rare: max grew a lot
            float sc = exp2f(m2 - l2);            // 0 on first edge
            sden *= sc;
#pragma unroll
            for (int r = 0; r < R; r++) acc[r] *= sc;
            m2 = l2;
        }
        float p = exp2f(l2 - m2);                 // common path: ONE exp2
        sden += p;
#pragma unroll
        for (int w2 = 0; w2 < W2; w2++) {
            acc[2 * w2 + 0] += p * (float)xv[w2][0];
            acc[2 * w2 + 1] += p * (float)xv[w2][1];
        }
#pragma unroll
        for (int w2 = 0; w2 < W2; w2++) xv[w2] = xn[w2];
    }

    const float rd = 1.f / sden;
#pragma unroll
    for (int r = 0; r < R; r++) {
        int c = lane * R + r;
        float v = acc[r] * rd + bias[c];
        if (RELU) v = fmaxf(v, 0.f);
        _Float16 h = (_Float16)v;
        oh[(size_t)i * HC + c] = h;
        ol[(size_t)i * HC + c] = (_Float16)(v - (float)h);
    }
}

// ---- LayerNorm over 256 features: wave per row -----------------------------
__global__ __launch_bounds__(256) void layernorm256(
    const float* __restrict__ x, const float* __restrict__ g,
    const float* __restrict__ b, float* __restrict__ out, int Nn)
{
    const int wave = threadIdx.x >> 6;
    const int lane = threadIdx.x & 63;
    const int i = blockIdx.x * 4 + wave;
    if (i >= Nn) return;
    float v[4];
    float sum = 0.f;
#pragma unroll
    for (int r = 0; r < 4; r++) {
        v[r] = x[(size_t)i * 256 + r * 64 + lane];
        sum += v[r];
    }
#pragma unroll
    for (int off = 32; off >= 1; off >>= 1) sum += __shfl_xor(sum, off);
    float mu = sum * (1.f / 256.f);
    float s2 = 0.f;
#pragma unroll
    for (int r = 0; r < 4; r++) { float d = v[r] - mu; s2 += d * d; }
#pragma unroll
    for (int off = 32; off >= 1; off >>= 1) s2 += __shfl_xor(s2, off);
    float rstd = 1.f / sqrtf(s2 * (1.f / 256.f) + 1e-5f);
#pragma unroll
    for (int r = 0; r < 4; r++) {
        int c = r * 64 + lane;
        out[(size_t)i * 256 + c] = (v[r] - mu) * rstd * g[c] + b[c];
    }
}

// ---------------------------------------------------------------------------
extern "C" void kernel_launch(void* const* d_in, const int* in_sizes, int n_in,
                              void* d_out, int out_size, void* d_ws,
                              size_t ws_size, hipStream_t stream)
{
    const float* node_f = (const float*)d_in[0];
    const float* msg_f  = (const float*)d_in[1];
    const int*   ei     = (const int*)d_in[2];
    const float* wsrc[12] = {
        (const float*)d_in[3],  (const float*)d_in[5],   // me_w1, me_w2
        (const float*)d_in[7],  (const float*)d_in[9],   // ne_w1, ne_w2
        (const float*)d_in[11], (const float*)d_in[12],  // c1_wl, c1_wr
        (const float*)d_in[15], (const float*)d_in[16],  // c2_wl, c2_wr
        (const float*)d_in[19], (const float*)d_in[20],  // c3_wl, c3_wr
        (const float*)d_in[23], (const float*)d_in[25],  // en_w1, en_w2
    };
    const int wsz[12] = {256*256, 128*256, 128*128, 128*128,
                         256*256, 256*256, 128*256, 128*256,
                         256*128, 256*128, 512*256, 256*512};
    const float* me_b1 = (const float*)d_in[4];
    const float* me_b2 = (const float*)d_in[6];
    const float* ne_b1 = (const float*)d_in[8];
    const float* ne_b2 = (const float*)d_in[10];
    const float* c1_at = (const float*)d_in[13];
    const float* c1_b  = (const float*)d_in[14];
    const float* c2_at = (const float*)d_in[17];
    const float* c2_b  = (const float*)d_in[18];
    const float* c3_at = (const float*)d_in[21];
    const float* c3_b  = (const float*)d_in[22];
    const float* en_b1 = (const float*)d_in[24];
    const float* en_b2 = (const float*)d_in[26];
    const float* ln_g  = (const float*)d_in[27];
    const float* ln_b  = (const float*)d_in[28];

    const int N  = in_sizes[0] / 128;   // 20000
    const int E  = in_sizes[2] / 2;     // 320000
    const int ET = E + N;

    // ---- workspace regions (each SZ = N*256*4 bytes) ----
    char* base = (char*)d_ws;
    const size_t SZ = (size_t)N * 256 * 4;
    char* RA = base;            // Pm pair            -> X1 pair (conv1 out)
    char* RB = base + SZ;       // Ph1 pair -> X3 pair (conv3 out) -> EN2 f32
    char* RC = base + 2 * SZ;   // Pn pair + Pnh pair -> X2 pair (conv2 out)
    char* RD = base + 3 * SZ;   // X0 pair (encoder concat out)
    char* RE = base + 4 * SZ;   // XLR fp16 (conv proj out) -> HB hi
    char* RF = base + 5 * SZ;   // HB lo
    char* RG = base + 6 * SZ;   // CSR ints + weight pairs

    _Float16* Pm_h = (_Float16*)RA;  _Float16* Pm_l = Pm_h + (size_t)N * 256;
    _Float16* X1_h = (_Float16*)RA;  _Float16* X1_l = X1_h + (size_t)N * 256;
    _Float16* Ph1_h = (_Float16*)RB; _Float16* Ph1_l = Ph1_h + (size_t)N * 256;
    _Float16* X3_h = (_Float16*)RB;  _Float16* X3_l = X3_h + (size_t)N * 256;
    float*    EN2  = (float*)RB;
    _Float16* Pn_h = (_Float16*)RC;  _Float16* Pn_l = Pn_h + (size_t)N * 128;
    _Float16* Pnh_h = Pn_l + (size_t)N * 128;
    _Float16* Pnh_l = Pnh_h + (size_t)N * 128;
    _Float16* X2_h = (_Float16*)RC;  _Float16* X2_l = X2_h + (size_t)N * 128;
    _Float16* X0_h = (_Float16*)RD;  _Float16* X0_l = X0_h + (size_t)N * 256;
    _Float16* XLR  = (_Float16*)RE;  // N x 512 max, fp16 [xl|xr]
    _Float16* HB_h = (_Float16*)RE;  // N x 512 halves
    _Float16* HB_l = (_Float16*)RF;

    int* CNT = (int*)RG;                     // N
    int* OFF = CNT + N;                      // N+1
    int* CUR = OFF + N + 1;                  // N
    int* SRCJ = CUR + N;                     // ET
    _Float16* WP = (_Float16*)(SRCJ + ET);

    // weight pair pointers; conv pairs stacked so [wl;wr] is one matrix
    _Float16 *wh[12], *wl[12];
    {
        _Float16* cur = WP;
        auto pair = [&](int i) { wh[i] = cur; cur += wsz[i]; wl[i] = cur; cur += wsz[i]; };
        pair(0); pair(1); pair(2); pair(3);
        auto stacked = [&](int i) {
            wh[i] = cur; wh[i+1] = cur + wsz[i]; cur += 2 * (size_t)wsz[i];
            wl[i] = cur; wl[i+1] = cur + wsz[i]; cur += 2 * (size_t)wsz[i];
        };
        stacked(4); stacked(6); stacked(8);
        pair(10); pair(11);
    }

    const dim3 B256(256);

    // ---- fused split: 12 weights + msg + node ----
    {
        SplitArgs sa;
        int cum = 0;
        for (int i = 0; i < 12; i++) {
            sa.src[i] = wsrc[i]; sa.dh[i] = wh[i]; sa.dl[i] = wl[i];
            sa.off[i] = cum; cum += wsz[i] / 4;
        }
        sa.src[12] = msg_f;  sa.dh[12] = Pm_h; sa.dl[12] = Pm_l;
        sa.off[12] = cum; cum += N * 256 / 4;
        sa.src[13] = node_f; sa.dh[13] = Pn_h; sa.dl[13] = Pn_l;
        sa.off[13] = cum; cum += N * 128 / 4;
        sa.off[14] = cum;
        split_multi<<<ceildiv(cum, 256), B256, 0, stream>>>(sa, cum);
    }

    // ---- CSR build (shared by all three convs) ----
    fill_u32<<<ceildiv(N, 256), B256, 0, stream>>>((unsigned int*)CNT, N, 0u);
    edge_count<<<ceildiv(ET, 256), B256, 0, stream>>>(ei, E, ET, CNT);
    scan_offsets<<<1, 1024, 0, stream>>>(CNT, N, OFF, CUR);
    edge_scatter<<<ceildiv(ET, 256), B256, 0, stream>>>(ei, E, ET, CUR, SRCJ);

    const int MB_ = ceildiv(N, 128);   // 157
    const int GGAT = ceildiv(N, 4);

    // ---- encoders -> X0 pair [N,256] = [node_emb | msg_emb] ----
    gemm_mfma<1, true ><<<dim3(4, MB_), B256, 0, stream>>>(
        Pm_h, Pm_l, wh[0], wl[0], me_b1, nullptr, Ph1_h, Ph1_l, N, 256, 256);
    gemm_mfma<1, false><<<dim3(2, MB_), B256, 0, stream>>>(
        Ph1_h, Ph1_l, wh[1], wl[1], me_b2, nullptr, X0_h + 128, X0_l + 128, N, 256, 256);
    gemm_mfma<1, true ><<<dim3(2, MB_), B256, 0, stream>>>(
        Pn_h, Pn_l, wh[2], wl[2], ne_b1, nullptr, Pnh_h, Pnh_l, N, 128, 128);
    gemm_mfma<1, false><<<dim3(2, MB_), B256, 0, stream>>>(
        Pnh_h, Pnh_l, wh[3], wl[3], ne_b2, nullptr, X0_h, X0_l, N, 128, 256);

    // ---- conv1: proj (512 cols fp16 [xl|xr]) + fused GAT ----
    gemm_mfma<2, false><<<dim3(8, MB_), B256, 0, stream>>>(
        X0_h, X0_l, wh[4], wl[4], nullptr, nullptr, XLR, nullptr, N, 256, 512);
    gat_fused<4, 64, true><<<GGAT, B256, 0, stream>>>(
        XLR, c1_at, c1_b, SRCJ, OFF, N, X1_h, X1_l);

    // ---- conv2: proj (256 cols) + fused GAT ----
    gemm_mfma<2, false><<<dim3(4, MB_), B256, 0, stream>>>(
        X1_h, X1_l, wh[6], wl[6], nullptr, nullptr, XLR, nullptr, N, 256, 256);
    gat_fused<2, 64, true><<<GGAT, B256, 0, stream>>>(
        XLR, c2_at, c2_b, SRCJ, OFF, N, X2_h, X2_l);

    // ---- conv3: proj (512 cols, K=128) + fused GAT ----
    gemm_mfma<2, false><<<dim3(8, MB_), B256, 0, stream>>>(
        X2_h, X2_l, wh[8], wl[8], nullptr, nullptr, XLR, nullptr, N, 128, 512);
    gat_fused<1, 256, false><<<GGAT, B256, 0, stream>>>(
        XLR, c3_at, c3_b, SRCJ, OFF, N, X3_h, X3_l);

    // ---- enhancer: X3 -> HB pair (512, relu) -> EN2 f32 -> LN -> d_out ----
    gemm_mfma<1, true ><<<dim3(8, MB_), B256, 0, stream>>>(
        X3_h, X3_l, wh[10], wl[10], en_b1, nullptr, HB_h, HB_l, N, 256, 512);
    gemm_mfma<0, false><<<dim3(4, MB_), B256, 0, stream>>>(
        HB_h, HB_l, wh[11], wl[11], en_b2, EN2, nullptr, nullptr, N, 512, 256);
    layernorm256<<<ceildiv(N, 4), B256, 0, stream>>>(EN2, ln_g, ln_b, (float*)d_out, N);
}

// Round 10
// 533.806 us; speedup vs baseline: 1.8333x; 1.0916x over previous
//
#include <hip/hip_runtime.h>
#include <math.h>

// ---------------------------------------------------------------------------
// StrategicGNN forward: MLP encoders -> 3x GATv2 -> MLP enhancer -> LayerNorm
// GEMMs: fp16x3-split MFMA (Ah*Wh + Ah*Wl + Al*Wh), global_load_lds staging.
// GAT: multi-edge-per-wave online softmax. Lane owns 16 feats; LPE=HC/16
// lanes per edge; EPW=64/LPE edges in flight per wave-iteration; per-lane
// flash state merged across edge-slots at the end (log2(EPW) shuffle steps).
// ---------------------------------------------------------------------------

static inline int ceildiv(int a, int b) { return (a + b - 1) / b; }

typedef _Float16 h8  __attribute__((ext_vector_type(8)));
typedef _Float16 h4v __attribute__((ext_vector_type(4)));
typedef _Float16 h2v __attribute__((ext_vector_type(2)));
typedef float    f4x __attribute__((ext_vector_type(4)));

__device__ __forceinline__ void gload16(const _Float16* g, _Float16* l) {
    __builtin_amdgcn_global_load_lds(
        (const __attribute__((address_space(1))) void*)g,
        (__attribute__((address_space(3))) void*)l, 16, 0, 0);
}

// ---- small utility ---------------------------------------------------------
__global__ void fill_u32(unsigned int* __restrict__ p, int n, unsigned int v) {
    int i = blockIdx.x * blockDim.x + threadIdx.x;
    if (i < n) p[i] = v;
}

// ---- fused hi/lo split of raw inputs + all weight matrices -----------------
struct SplitArgs {
    const float* src[14];
    _Float16* dh[14];
    _Float16* dl[14];
    int off[15];          // prefix sums, float4 units
};

__global__ void split_multi(SplitArgs a, int totalv) {
    int v = blockIdx.x * blockDim.x + threadIdx.x;
    if (v >= totalv) return;
    int s = 0;
#pragma unroll
    for (int i = 1; i < 14; i++) s += (v >= a.off[i]);
    int lv = v - a.off[s];
    float4 f = ((const float4*)a.src[s])[lv];
    float vals[4] = {f.x, f.y, f.z, f.w};
    h4v hh, hl;
#pragma unroll
    for (int j = 0; j < 4; j++) {
        _Float16 h = (_Float16)vals[j];
        hh[j] = h;
        hl[j] = (_Float16)(vals[j] - (float)h);
    }
    *(h4v*)(a.dh[s] + (size_t)lv * 4) = hh;
    *(h4v*)(a.dl[s] + (size_t)lv * 4) = hl;
}

// ---- MFMA GEMM: C[M,*] = act(A[M,K] @ W[*,K]^T + bias) ---------------------
// Tile 128x64, BK=64, 4 waves (64x32 each). A,W staged via global_load_lds
// (linear LDS dest) with inverse-XOR-swizzled global source; reads apply the
// same 16B-chunk XOR (involution) -> bank-conflict-free ds_read_b128.
// OUT 0: fp32 Cf. OUT 1: fp16 hi/lo pair Chi/Clo. OUT 2: fp16 single Chi.
template <int OUT, bool RELU>
__global__ __launch_bounds__(256) void gemm_mfma(
    const _Float16* __restrict__ Ahi, const _Float16* __restrict__ Alo,
    const _Float16* __restrict__ Whi, const _Float16* __restrict__ Wlo,
    const float* __restrict__ bias, float* __restrict__ Cf,
    _Float16* __restrict__ Chi, _Float16* __restrict__ Clo,
    int M, int K, int ldc)
{
    __shared__ _Float16 sA[2][128][64];   // [hi/lo][row][k]
    __shared__ _Float16 sW[2][64][64];
    const int t = threadIdx.x;
    const int lane = t & 63;
    const int w = t >> 6, wr = w >> 1, wc = w & 1;   // 2x2 waves of 64x32
    const int m0 = blockIdx.y * 128, n0 = blockIdx.x * 64;

    f4x acc[4][2] = {};

    for (int k0 = 0; k0 < K; k0 += 64) {
        // A tile: v = bv + lane; row = v>>3, lds chunk = lane&7 (linear dest);
        // global source chunk = (lane&7) ^ (row&7)  [involution]
#pragma unroll
        for (int i = 0; i < 4; i++) {
            const int bv = w * 64 + i * 256;          // wave-uniform
            const int row = (bv >> 3) + (lane >> 3);
            const int c8 = (lane & 7) ^ (row & 7);
            int gr = m0 + row; if (gr > M - 1) gr = M - 1;   // clamp tail
            const size_t g = (size_t)gr * K + k0 + c8 * 8;
            gload16(Ahi + g, &sA[0][0][0] + (size_t)bv * 8);
            gload16(Alo + g, &sA[1][0][0] + (size_t)bv * 8);
        }
#pragma unroll
        for (int i = 0; i < 2; i++) {
            const int bv = w * 64 + i * 256;
            const int row = (bv >> 3) + (lane >> 3);
            const int c8 = (lane & 7) ^ (row & 7);
            const size_t g = (size_t)(n0 + row) * K + k0 + c8 * 8;
            gload16(Whi + g, &sW[0][0][0] + (size_t)bv * 8);
            gload16(Wlo + g, &sW[1][0][0] + (size_t)bv * 8);
        }
        __syncthreads();                 // drains vmcnt (m97 pattern)
#pragma unroll
        for (int ks = 0; ks < 2; ks++) {        // two K=32 slices per BK=64
            const int kg = ks * 4 + (lane >> 4);   // 16B chunk index along k
            h8 afh[4], afl[4], wfh[2], wfl[2];
#pragma unroll
            for (int mi = 0; mi < 4; mi++) {
                int row = wr * 64 + mi * 16 + (lane & 15);
                int cs = ((kg ^ (row & 7)) << 3);
                afh[mi] = *(const h8*)&sA[0][row][cs];
                afl[mi] = *(const h8*)&sA[1][row][cs];
            }
#pragma unroll
            for (int ni = 0; ni < 2; ni++) {
                int row = wc * 32 + ni * 16 + (lane & 15);
                int cs = ((kg ^ (row & 7)) << 3);
                wfh[ni] = *(const h8*)&sW[0][row][cs];
                wfl[ni] = *(const h8*)&sW[1][row][cs];
            }
#pragma unroll
            for (int mi = 0; mi < 4; mi++)
#pragma unroll
                for (int ni = 0; ni < 2; ni++) {
                    acc[mi][ni] = __builtin_amdgcn_mfma_f32_16x16x32_f16(
                        afh[mi], wfh[ni], acc[mi][ni], 0, 0, 0);
                    acc[mi][ni] = __builtin_amdgcn_mfma_f32_16x16x32_f16(
                        afh[mi], wfl[ni], acc[mi][ni], 0, 0, 0);
                    acc[mi][ni] = __builtin_amdgcn_mfma_f32_16x16x32_f16(
                        afl[mi], wfh[ni], acc[mi][ni], 0, 0, 0);
                }
        }
        __syncthreads();
    }
    // epilogue: C/D layout col=lane&15, row=(lane>>4)*4+reg  [m89-verified]
#pragma unroll
    for (int mi = 0; mi < 4; mi++) {
#pragma unroll
        for (int ni = 0; ni < 2; ni++) {
            int col = n0 + wc * 32 + ni * 16 + (lane & 15);
            float bz = bias ? bias[col] : 0.f;
#pragma unroll
            for (int r = 0; r < 4; r++) {
                int grow = m0 + wr * 64 + mi * 16 + (lane >> 4) * 4 + r;
                if (grow < M) {
                    float vv = acc[mi][ni][r] + bz;
                    if (RELU) vv = fmaxf(vv, 0.f);
                    if (OUT == 0) {
                        Cf[(size_t)grow * ldc + col] = vv;
                    } else if (OUT == 1) {
                        _Float16 h = (_Float16)vv;
                        Chi[(size_t)grow * ldc + col] = h;
                        Clo[(size_t)grow * ldc + col] = (_Float16)(vv - (float)h);
                    } else {
                        Chi[(size_t)grow * ldc + col] = (_Float16)vv;
                    }
                }
            }
        }
    }
}

// ---- CSR build (dst-sorted incidence; self-loop e in [E, E+N) ) ------------
__global__ void edge_count(const int* __restrict__ ei, int E, int ET,
                           int* __restrict__ cnt) {
    int e = blockIdx.x * blockDim.x + threadIdx.x;
    if (e >= ET) return;
    int dst = (e < E) ? ei[E + e] : e - E;
    atomicAdd(&cnt[dst], 1);
}

__global__ __launch_bounds__(1024) void scan_offsets(
    const int* __restrict__ cnt, int n, int* __restrict__ off,
    int* __restrict__ cur)
{
    __shared__ int s[1024];
    const int t = threadIdx.x;
    const int CH = (n + 1023) / 1024;
    int base = t * CH;
    int local[32];
    int sum = 0;
    for (int j = 0; j < CH; j++) {
        int idx = base + j;
        int v = (idx < n) ? cnt[idx] : 0;
        local[j] = sum;
        sum += v;
    }
    s[t] = sum;
    __syncthreads();
    for (int d = 1; d < 1024; d <<= 1) {
        int v = (t >= d) ? s[t - d] : 0;
        __syncthreads();
        s[t] += v;
        __syncthreads();
    }
    int excl = s[t] - sum;
    for (int j = 0; j < CH; j++) {
        int idx = base + j;
        if (idx < n) { off[idx] = excl + local[j]; cur[idx] = excl + local[j]; }
    }
    if (t == 1023) off[n] = s[1023];
}

// scatter src ids into dst-sorted CSR order
__global__ void edge_scatter(const int* __restrict__ ei, int E, int ET,
                             int* __restrict__ cur, int* __restrict__ srcj) {
    int e = blockIdx.x * blockDim.x + threadIdx.x;
    if (e >= ET) return;
    int dst, src;
    if (e < E) { dst = ei[E + e]; src = ei[e]; } else { dst = src = e - E; }
    int pos = atomicAdd(&cur[dst], 1);
    srcj[pos] = src;
}

// ---- fused GATv2 layer: wave per dst node, multi-edge per iteration --------
// xlr = fp16 [Nn, 2*H*C] = [xl | xr]. Lane owns feats [l*16, l*16+16) of
// edge-slot g (lane = g*LPE + l). EPW edges processed per iteration with
// per-lane online-softmax state; states flash-merged across slots at end.
template <int H, int C, bool RELU>
__global__ __launch_bounds__(256) void gat_fused(
    const _Float16* __restrict__ xlr,
    const float* __restrict__ att, const float* __restrict__ bias,
    const int* __restrict__ srcj, const int* __restrict__ off, int Nn,
    _Float16* __restrict__ oh, _Float16* __restrict__ ol)
{
    constexpr int HC = H * C;
    constexpr int LD = 2 * HC;
    constexpr int LPE = HC / 16;              // lanes per edge (16, 8, 16)
    constexpr int EPW = 64 / LPE;             // edge slots per wave (4, 8, 4)
    constexpr int SUB = C / 16;               // lanes per head (4, 4, 16)
    constexpr float L2E = 1.44269504088896f;
    constexpr float THR = 12.0f;              // defer-max threshold (log2)
    const int wave = threadIdx.x >> 6;
    const int lane = threadIdx.x & 63;
    const int g = lane / LPE;                 // edge slot
    const int l = lane % LPE;                 // lane within edge
    const int i = blockIdx.x * 4 + wave;
    if (i >= Nn) return;
    const int j0 = off[i], j1 = off[i + 1];

    // per-lane constants: xr + att for feats [l*16, l*16+16) (same for all g)
    h8 xr8[2];
    xr8[0] = *(const h8*)(xlr + (size_t)i * LD + HC + l * 16);
    xr8[1] = *(const h8*)(xlr + (size_t)i * LD + HC + l * 16 + 8);
    const h2v* xr2 = (const h2v*)xr8;
    h2v at2[8];
#pragma unroll
    for (int q = 0; q < 8; q++) {
        int c = l * 16 + 2 * q;
        h2v a; a[0] = (_Float16)att[c]; a[1] = (_Float16)att[c + 1];
        at2[q] = a;
    }

    float m2 = -INFINITY, sden = 0.f;
    float acc[16] = {};

    for (int jb = j0; jb < j1; jb += EPW) {
        const int j = jb + g;
        const bool valid = (j < j1);
        const int jj = valid ? j : j1 - 1;
        const int s = srcj[jj];
        h8 xa[2];
        const _Float16* xp = xlr + (size_t)s * LD + l * 16;
        xa[0] = *(const h8*)xp;
        xa[1] = *(const h8*)(xp + 8);
        const h2v* xv2 = (const h2v*)xa;

        float dot = 0.f;
#pragma unroll
        for (int q = 0; q < 8; q++) {
            h2v v = xv2[q] + xr2[q];
            h2v s5 = v * (_Float16)0.2f;
            h2v lk;
            lk[0] = v[0] > (_Float16)0 ? v[0] : s5[0];
            lk[1] = v[1] > (_Float16)0 ? v[1] : s5[1];
            dot = __builtin_amdgcn_fdot2(lk, at2[q], dot, false);
        }
#pragma unroll
        for (int d = 1; d < SUB; d <<= 1) dot += __shfl_xor(dot, d);
        float l2 = dot * L2E;
        if (!valid) l2 = -1e30f;               // p underflows to 0 below

        if (l2 - m2 > THR) {                   // rare: max grew a lot
            float sc = exp2f(m2 - l2);         // 0 on first edge
            sden *= sc;
#pragma unroll
            for (int r = 0; r < 16; r++) acc[r] *= sc;
            m2 = l2;
        }
        float p = exp2f(l2 - m2);              // common path: ONE exp2
        sden += p;
#pragma unroll
        for (int q = 0; q < 8; q++) {
            acc[2 * q + 0] += p * (float)xv2[q][0];
            acc[2 * q + 1] += p * (float)xv2[q][1];
        }
    }

    // flash-merge the EPW edge-slot states (same l => same feats+head)
#pragma unroll
    for (int d = LPE; d < 64; d <<= 1) {
        float m2o = __shfl_xor(m2, d);
        float sdo = __shfl_xor(sden, d);
        float mn = fmaxf(m2, m2o);
        float sa = exp2f(m2 - mn), sb = exp2f(m2o - mn);
#pragma unroll
        for (int r = 0; r < 16; r++) {
            float ao = __shfl_xor(acc[r], d);
            acc[r] = acc[r] * sa + ao * sb;
        }
        sden = sden * sa + sdo * sb;
        m2 = mn;
    }

    if (g == 0) {
        const float rd = 1.f / sden;
        h8 vh[2], vl[2];
#pragma unroll
        for (int r = 0; r < 16; r++) {
            int c = l * 16 + r;
            float v = acc[r] * rd + bias[c];
            if (RELU) v = fmaxf(v, 0.f);
            _Float16 hh = (_Float16)v;
            vh[r >> 3][r & 7] = hh;
            vl[r >> 3][r & 7] = (_Float16)(v - (float)hh);
        }
        *(h8*)(oh + (size_t)i * HC + l * 16) = vh[0];
        *(h8*)(oh + (size_t)i * HC + l * 16 + 8) = vh[1];
        *(h8*)(ol + (size_t)i * HC + l * 16) = vl[0];
        *(h8*)(ol + (size_t)i * HC + l * 16 + 8) = vl[1];
    }
}

// ---- LayerNorm over 256 features: wave per row -----------------------------
__global__ __launch_bounds__(256) void layernorm256(
    const float* __restrict__ x, const float* __restrict__ g,
    const float* __restrict__ b, float* __restrict__ out, int Nn)
{
    const int wave = threadIdx.x >> 6;
    const int lane = threadIdx.x & 63;
    const int i = blockIdx.x * 4 + wave;
    if (i >= Nn) return;
    float v[4];
    float sum = 0.f;
#pragma unroll
    for (int r = 0; r < 4; r++) {
        v[r] = x[(size_t)i * 256 + r * 64 + lane];
        sum += v[r];
    }
#pragma unroll
    for (int off = 32; off >= 1; off >>= 1) sum += __shfl_xor(sum, off);
    float mu = sum * (1.f / 256.f);
    float s2 = 0.f;
#pragma unroll
    for (int r = 0; r < 4; r++) { float d = v[r] - mu; s2 += d * d; }
#pragma unroll
    for (int off = 32; off >= 1; off >>= 1) s2 += __shfl_xor(s2, off);
    float rstd = 1.f / sqrtf(s2 * (1.f / 256.f) + 1e-5f);
#pragma unroll
    for (int r = 0; r < 4; r++) {
        int c = r * 64 + lane;
        out[(size_t)i * 256 + c] = (v[r] - mu) * rstd * g[c] + b[c];
    }
}

// ---------------------------------------------------------------------------
extern "C" void kernel_launch(void* const* d_in, const int* in_sizes, int n_in,
                              void* d_out, int out_size, void* d_ws,
                              size_t ws_size, hipStream_t stream)
{
    const float* node_f = (const float*)d_in[0];
    const float* msg_f  = (const float*)d_in[1];
    const int*   ei     = (const int*)d_in[2];
    const float* wsrc[12] = {
        (const float*)d_in[3],  (const float*)d_in[5],   // me_w1, me_w2
        (const float*)d_in[7],  (const float*)d_in[9],   // ne_w1, ne_w2
        (const float*)d_in[11], (const float*)d_in[12],  // c1_wl, c1_wr
        (const float*)d_in[15], (const float*)d_in[16],  // c2_wl, c2_wr
        (const float*)d_in[19], (const float*)d_in[20],  // c3_wl, c3_wr
        (const float*)d_in[23], (const float*)d_in[25],  // en_w1, en_w2
    };
    const int wsz[12] = {256*256, 128*256, 128*128, 128*128,
                         256*256, 256*256, 128*256, 128*256,
                         256*128, 256*128, 512*256, 256*512};
    const float* me_b1 = (const float*)d_in[4];
    const float* me_b2 = (const float*)d_in[6];
    const float* ne_b1 = (const float*)d_in[8];
    const float* ne_b2 = (const float*)d_in[10];
    const float* c1_at = (const float*)d_in[13];
    const float* c1_b  = (const float*)d_in[14];
    const float* c2_at = (const float*)d_in[17];
    const float* c2_b  = (const float*)d_in[18];
    const float* c3_at = (const float*)d_in[21];
    const float* c3_b  = (const float*)d_in[22];
    const float* en_b1 = (const float*)d_in[24];
    const float* en_b2 = (const float*)d_in[26];
    const float* ln_g  = (const float*)d_in[27];
    const float* ln_b  = (const float*)d_in[28];

    const int N  = in_sizes[0] / 128;   // 20000
    const int E  = in_sizes[2] / 2;     // 320000
    const int ET = E + N;

    // ---- workspace regions (each SZ = N*256*4 bytes) ----
    char* base = (char*)d_ws;
    const size_t SZ = (size_t)N * 256 * 4;
    char* RA = base;            // Pm pair            -> X1 pair (conv1 out)
    char* RB = base + SZ;       // Ph1 pair -> X3 pair (conv3 out) -> EN2 f32
    char* RC = base + 2 * SZ;   // Pn pair + Pnh pair -> X2 pair (conv2 out)
    char* RD = base + 3 * SZ;   // X0 pair (encoder concat out)
    char* RE = base + 4 * SZ;   // XLR fp16 (conv proj out) -> HB hi
    char* RF = base + 5 * SZ;   // HB lo
    char* RG = base + 6 * SZ;   // CSR ints + weight pairs

    _Float16* Pm_h = (_Float16*)RA;  _Float16* Pm_l = Pm_h + (size_t)N * 256;
    _Float16* X1_h = (_Float16*)RA;  _Float16* X1_l = X1_h + (size_t)N * 256;
    _Float16* Ph1_h = (_Float16*)RB; _Float16* Ph1_l = Ph1_h + (size_t)N * 256;
    _Float16* X3_h = (_Float16*)RB;  _Float16* X3_l = X3_h + (size_t)N * 256;
    float*    EN2  = (float*)RB;
    _Float16* Pn_h = (_Float16*)RC;  _Float16* Pn_l = Pn_h + (size_t)N * 128;
    _Float16* Pnh_h = Pn_l + (size_t)N * 128;
    _Float16* Pnh_l = Pnh_h + (size_t)N * 128;
    _Float16* X2_h = (_Float16*)RC;  _Float16* X2_l = X2_h + (size_t)N * 128;
    _Float16* X0_h = (_Float16*)RD;  _Float16* X0_l = X0_h + (size_t)N * 256;
    _Float16* XLR  = (_Float16*)RE;  // N x 512 max, fp16 [xl|xr]
    _Float16* HB_h = (_Float16*)RE;  // N x 512 halves
    _Float16* HB_l = (_Float16*)RF;

    int* CNT = (int*)RG;                     // N
    int* OFF = CNT + N;                      // N+1
    int* CUR = OFF + N + 1;                  // N
    int* SRCJ = CUR + N;                     // ET
    _Float16* WP = (_Float16*)(SRCJ + ET);

    // weight pair pointers; conv pairs stacked so [wl;wr] is one matrix
    _Float16 *wh[12], *wl[12];
    {
        _Float16* cur = WP;
        auto pair = [&](int i) { wh[i] = cur; cur += wsz[i]; wl[i] = cur; cur += wsz[i]; };
        pair(0); pair(1); pair(2); pair(3);
        auto stacked = [&](int i) {
            wh[i] = cur; wh[i+1] = cur + wsz[i]; cur += 2 * (size_t)wsz[i];
            wl[i] = cur; wl[i+1] = cur + wsz[i]; cur += 2 * (size_t)wsz[i];
        };
        stacked(4); stacked(6); stacked(8);
        pair(10); pair(11);
    }

    const dim3 B256(256);

    // ---- fused split: 12 weights + msg + node ----
    {
        SplitArgs sa;
        int cum = 0;
        for (int i = 0; i < 12; i++) {
            sa.src[i] = wsrc[i]; sa.dh[i] = wh[i]; sa.dl[i] = wl[i];
            sa.off[i] = cum; cum += wsz[i] / 4;
        }
        sa.src[12] = msg_f;  sa.dh[12] = Pm_h; sa.dl[12] = Pm_l;
        sa.off[12] = cum; cum += N * 256 / 4;
        sa.src[13] = node_f; sa.dh[13] = Pn_h; sa.dl[13] = Pn_l;
        sa.off[13] = cum; cum += N * 128 / 4;
        sa.off[14] = cum;
        split_multi<<<ceildiv(cum, 256), B256, 0, stream>>>(sa, cum);
    }

    // ---- CSR build (shared by all three convs) ----
    fill_u32<<<ceildiv(N, 256), B256, 0, stream>>>((unsigned int*)CNT, N, 0u);
    edge_count<<<ceildiv(ET, 256), B256, 0, stream>>>(ei, E, ET, CNT);
    scan_offsets<<<1, 1024, 0, stream>>>(CNT, N, OFF, CUR);
    edge_scatter<<<ceildiv(ET, 256), B256, 0, stream>>>(ei, E, ET, CUR, SRCJ);

    const int MB_ = ceildiv(N, 128);   // 157
    const int GGAT = ceildiv(N, 4);

    // ---- encoders -> X0 pair [N,256] = [node_emb | msg_emb] ----
    gemm_mfma<1, true ><<<dim3(4, MB_), B256, 0, stream>>>(
        Pm_h, Pm_l, wh[0], wl[0], me_b1, nullptr, Ph1_h, Ph1_l, N, 256, 256);
    gemm_mfma<1, false><<<dim3(2, MB_), B256, 0, stream>>>(
        Ph1_h, Ph1_l, wh[1], wl[1], me_b2, nullptr, X0_h + 128, X0_l + 128, N, 256, 256);
    gemm_mfma<1, true ><<<dim3(2, MB_), B256, 0, stream>>>(
        Pn_h, Pn_l, wh[2], wl[2], ne_b1, nullptr, Pnh_h, Pnh_l, N, 128, 128);
    gemm_mfma<1, false><<<dim3(2, MB_), B256, 0, stream>>>(
        Pnh_h, Pnh_l, wh[3], wl[3], ne_b2, nullptr, X0_h, X0_l, N, 128, 256);

    // ---- conv1: proj (512 cols fp16 [xl|xr]) + fused GAT ----
    gemm_mfma<2, false><<<dim3(8, MB_), B256, 0, stream>>>(
        X0_h, X0_l, wh[4], wl[4], nullptr, nullptr, XLR, nullptr, N, 256, 512);
    gat_fused<4, 64, true><<<GGAT, B256, 0, stream>>>(
        XLR, c1_at, c1_b, SRCJ, OFF, N, X1_h, X1_l);

    // ---- conv2: proj (256 cols) + fused GAT ----
    gemm_mfma<2, false><<<dim3(4, MB_), B256, 0, stream>>>(
        X1_h, X1_l, wh[6], wl[6], nullptr, nullptr, XLR, nullptr, N, 256, 256);
    gat_fused<2, 64, true><<<GGAT, B256, 0, stream>>>(
        XLR, c2_at, c2_b, SRCJ, OFF, N, X2_h, X2_l);

    // ---- conv3: proj (512 cols, K=128) + fused GAT ----
    gemm_mfma<2, false><<<dim3(8, MB_), B256, 0, stream>>>(
        X2_h, X2_l, wh[8], wl[8], nullptr, nullptr, XLR, nullptr, N, 128, 512);
    gat_fused<1, 256, false><<<GGAT, B256, 0, stream>>>(
        XLR, c3_at, c3_b, SRCJ, OFF, N, X3_h, X3_l);

    // ---- enhancer: X3 -> HB pair (512, relu) -> EN2 f32 -> LN -> d_out ----
    gemm_mfma<1, true ><<<dim3(8, MB_), B256, 0, stream>>>(
        X3_h, X3_l, wh[10], wl[10], en_b1, nullptr, HB_h, HB_l, N, 256, 512);
    gemm_mfma<0, false><<<dim3(4, MB_), B256, 0, stream>>>(
        HB_h, HB_l, wh[11], wl[11], en_b2, EN2, nullptr, nullptr, N, 512, 256);
    layernorm256<<<ceildiv(N, 4), B256, 0, stream>>>(EN2, ln_g, ln_b, (float*)d_out, N);
}